// Round 1
// baseline (9855.931 us; speedup 1.0000x reference)
//
#include <hip/hip_runtime.h>
#include <hip/hip_bf16.h>

// Problem constants (match reference)
#define NN 50000
#define NE 500000
// D_NODE=64, D_EDGE=8, D_MSG=64, H_MSG=128, H_UPD=64, H_TEN=32, D_OUT=32

__device__ __forceinline__ float bcastf(float v, int k) {
    return __builtin_bit_cast(float, __builtin_amdgcn_readlane(__builtin_bit_cast(int, v), k));
}

// ---------------------------------------------------------------------------
// Edge kernel: one wave per original edge (computes BOTH directions).
//   in_fwd = [x[t]-x[s], ea],  in_bwd = -in_fwd
//   z = in_fwd @ Wm1  (shared between directions)
//   h_fwd = relu(z+bm1), h_bwd = relu(-z+bm1)
//   m_fwd = relu(h_fwd@Wm2+bm2) -> atomic into sums[t]; m_bwd -> sums[s]
//   e_out[e] = tension MLP on (m_fwd + m_bwd)
// ---------------------------------------------------------------------------
__global__ __launch_bounds__(1024) void edge_kernel(
    const float* __restrict__ x, const int* __restrict__ ei,
    const float* __restrict__ ea,
    const float* __restrict__ Wm1, const float* __restrict__ bm1,
    const float* __restrict__ Wm2, const float* __restrict__ bm2,
    const float* __restrict__ Wt1, const float* __restrict__ bt1,
    const float* __restrict__ Wt2, const float* __restrict__ bt2,
    float* __restrict__ sums, float* __restrict__ cnt,
    float* __restrict__ e_out)
{
    __shared__ float wm1[72 * 128];   // 36.9 KB
    __shared__ float wm2[128 * 64];   // 32.8 KB
    __shared__ float wt1[64 * 32];    //  8.2 KB
    __shared__ float bm1s[128], bm2s[64], bt1s[32], wt2s[32];

    const int tid = threadIdx.x;
    for (int i = tid; i < 72 * 128; i += 1024) wm1[i] = Wm1[i];
    for (int i = tid; i < 128 * 64; i += 1024) wm2[i] = Wm2[i];
    for (int i = tid; i < 64 * 32; i += 1024) wt1[i] = Wt1[i];
    if (tid < 128) bm1s[tid] = bm1[tid];
    if (tid < 64)  bm2s[tid] = bm2[tid];
    if (tid < 32)  { bt1s[tid] = bt1[tid]; wt2s[tid] = Wt2[tid]; }
    __syncthreads();

    const float bt2v = bt2[0];
    const int lane = tid & 63;
    const int wid  = tid >> 6;
    const int gw   = blockIdx.x * 16 + wid;
    const int nw   = gridDim.x * 16;

    for (int e = gw; e < NE; e += nw) {
        const int s = ei[e];
        const int t = ei[NE + e];
        // lane i holds input element i (diff), lanes 0..7 also hold edge_attr
        const float diff = x[t * 64 + lane] - x[s * 64 + lane];
        const float eav  = (lane < 8) ? ea[e * 8 + lane] : 0.f;

        // ---- layer 1: z[j] = in @ Wm1, lane holds j=lane and j=lane+64 ----
        float z0 = 0.f, z1 = 0.f;
#pragma unroll
        for (int k = 0; k < 64; ++k) {
            const float a = bcastf(diff, k);
            z0 = fmaf(a, wm1[k * 128 + lane], z0);
            z1 = fmaf(a, wm1[k * 128 + 64 + lane], z1);
        }
#pragma unroll
        for (int k = 0; k < 8; ++k) {
            const float a = bcastf(eav, k);
            z0 = fmaf(a, wm1[(64 + k) * 128 + lane], z0);
            z1 = fmaf(a, wm1[(64 + k) * 128 + 64 + lane], z1);
        }
        const float b0 = bm1s[lane], b1 = bm1s[64 + lane];
        const float hf0 = fmaxf(z0 + b0, 0.f), hf1 = fmaxf(z1 + b1, 0.f);
        const float hb0 = fmaxf(b0 - z0, 0.f), hb1 = fmaxf(b1 - z1, 0.f);

        // ---- layer 2: m[j] = h @ Wm2, lane holds j=lane (64 outputs) ----
        float mf = 0.f, mb = 0.f;
#pragma unroll
        for (int k = 0; k < 64; ++k) {
            const float w = wm2[k * 64 + lane];
            mf = fmaf(bcastf(hf0, k), w, mf);
            mb = fmaf(bcastf(hb0, k), w, mb);
        }
#pragma unroll
        for (int k = 0; k < 64; ++k) {
            const float w = wm2[(64 + k) * 64 + lane];
            mf = fmaf(bcastf(hf1, k), w, mf);
            mb = fmaf(bcastf(hb1, k), w, mb);
        }
        const float bb = bm2s[lane];
        mf = fmaxf(mf + bb, 0.f);
        mb = fmaxf(mb + bb, 0.f);

        // ---- scatter-sum (mean finished in node kernel) ----
        atomicAdd(&sums[t * 64 + lane], mf);
        atomicAdd(&sums[s * 64 + lane], mb);
        if (lane == 0) {
            atomicAdd(&cnt[t], 1.f);
            atomicAdd(&cnt[s], 1.f);
        }

        // ---- tension MLP on m_sym = mf + mb ----
        const float msym = mf + mb;           // lane k holds m_sym[k]
        const int j = lane & 31;              // lanes 32..63 duplicate 0..31
        float htv = 0.f;
#pragma unroll
        for (int k = 0; k < 64; ++k) {
            htv = fmaf(bcastf(msym, k), wt1[k * 32 + j], htv);
        }
        htv = fmaxf(htv + bt1s[j], 0.f);
        float p = htv * wt2s[j];
        // reduce over 32 lanes (xor masks stay within each 32-half)
        p += __shfl_xor(p, 1, 64);
        p += __shfl_xor(p, 2, 64);
        p += __shfl_xor(p, 4, 64);
        p += __shfl_xor(p, 8, 64);
        p += __shfl_xor(p, 16, 64);
        if (lane == 0) e_out[e] = p + bt2v;
    }
}

// ---------------------------------------------------------------------------
// Node kernel: one wave per node. aggr = sums/max(cnt,1); 2-layer update MLP.
// ---------------------------------------------------------------------------
__global__ __launch_bounds__(1024) void node_kernel(
    const float* __restrict__ x,
    const float* __restrict__ Wu1, const float* __restrict__ bu1,
    const float* __restrict__ Wu2, const float* __restrict__ bu2,
    const float* __restrict__ sums, const float* __restrict__ cnt,
    float* __restrict__ x_out)
{
    __shared__ float wu1[128 * 64];   // 32.8 KB
    __shared__ float wu2[64 * 32];    //  8.2 KB
    __shared__ float bu1s[64], bu2s[32];

    const int tid = threadIdx.x;
    for (int i = tid; i < 128 * 64; i += 1024) wu1[i] = Wu1[i];
    for (int i = tid; i < 64 * 32; i += 1024) wu2[i] = Wu2[i];
    if (tid < 64) bu1s[tid] = bu1[tid];
    if (tid < 32) bu2s[tid] = bu2[tid];
    __syncthreads();

    const int lane = tid & 63;
    const int wid  = tid >> 6;
    const int gw   = blockIdx.x * 16 + wid;
    const int nw   = gridDim.x * 16;

    for (int i = gw; i < NN; i += nw) {
        const float xv = x[i * 64 + lane];
        const float c  = cnt[i];
        const float inv = 1.f / fmaxf(c, 1.f);
        const float av = sums[i * 64 + lane] * inv;

        float z = bu1s[lane];
#pragma unroll
        for (int k = 0; k < 64; ++k) {
            z = fmaf(bcastf(xv, k), wu1[k * 64 + lane], z);
        }
#pragma unroll
        for (int k = 0; k < 64; ++k) {
            z = fmaf(bcastf(av, k), wu1[(64 + k) * 64 + lane], z);
        }
        const float hu = fmaxf(z, 0.f);

        const int j = lane & 31;
        float o = 0.f;
#pragma unroll
        for (int k = 0; k < 64; ++k) {
            o = fmaf(bcastf(hu, k), wu2[k * 32 + j], o);
        }
        if (lane < 32) x_out[i * 32 + j] = o + bu2s[j];
    }
}

extern "C" void kernel_launch(void* const* d_in, const int* in_sizes, int n_in,
                              void* d_out, int out_size, void* d_ws, size_t ws_size,
                              hipStream_t stream) {
    const float* x   = (const float*)d_in[0];
    const int*   ei  = (const int*)d_in[1];     // harness converts int64 -> int32
    const float* ea  = (const float*)d_in[2];
    const float* Wm1 = (const float*)d_in[3];
    const float* bm1 = (const float*)d_in[4];
    const float* Wm2 = (const float*)d_in[5];
    const float* bm2 = (const float*)d_in[6];
    const float* Wu1 = (const float*)d_in[7];
    const float* bu1 = (const float*)d_in[8];
    const float* Wu2 = (const float*)d_in[9];
    const float* bu2 = (const float*)d_in[10];
    const float* Wt1 = (const float*)d_in[11];
    const float* bt1 = (const float*)d_in[12];
    const float* Wt2 = (const float*)d_in[13];
    const float* bt2 = (const float*)d_in[14];

    float* sums = (float*)d_ws;          // [NN * 64]
    float* cnt  = sums + (size_t)NN * 64; // [NN]
    float* x_out = (float*)d_out;         // [NN * 32]
    float* e_out = x_out + (size_t)NN * 32; // [NE]

    // zero the scatter accumulators (ws is re-poisoned before every launch)
    hipMemsetAsync(d_ws, 0, ((size_t)NN * 64 + NN) * sizeof(float), stream);

    edge_kernel<<<512, 1024, 0, stream>>>(x, ei, ea, Wm1, bm1, Wm2, bm2,
                                          Wt1, bt1, Wt2, bt2, sums, cnt, e_out);
    node_kernel<<<256, 1024, 0, stream>>>(x, Wu1, bu1, Wu2, bu2, sums, cnt, x_out);
}

// Round 2
// 6973.117 us; speedup vs baseline: 1.4134x; 1.4134x over previous
//
#include <hip/hip_runtime.h>
#include <hip/hip_bf16.h>

// Problem constants (match reference)
#define NN 50000
#define NE 500000
// D_NODE=64, D_EDGE=8, D_MSG=64, H_MSG=128, H_UPD=64, H_TEN=32, D_OUT=32

__device__ __forceinline__ float bcastf(float v, int k) {
    return __builtin_bit_cast(float, __builtin_amdgcn_readlane(__builtin_bit_cast(int, v), k));
}

// ===========================================================================
// CSR-build kernels (directed edge d in [0,2E): d<NE fwd tgt=ei[NE+d];
//                    d>=NE bwd tgt=ei[d-NE])
// ===========================================================================
__global__ void hist_kernel(const int* __restrict__ ei, int* __restrict__ deg) {
    int e = blockIdx.x * blockDim.x + threadIdx.x;
    if (e < NE) {
        atomicAdd(&deg[ei[NE + e]], 1);   // fwd message targets t
        atomicAdd(&deg[ei[e]], 1);        // bwd message targets s
    }
}

__global__ __launch_bounds__(1024) void scan_kernel(
    const int* __restrict__ deg, int* __restrict__ off, int* __restrict__ cursor) {
    __shared__ int part[1024];
    const int C = (NN + 1023) / 1024;     // 49
    const int tid = threadIdx.x;
    const int base = tid * C;
    const int lim = min(base + C, NN);
    int s = 0;
    for (int i = base; i < lim; ++i) s += deg[i];
    part[tid] = s;
    __syncthreads();
    // Hillis-Steele inclusive scan over 1024 partials
    for (int d = 1; d < 1024; d <<= 1) {
        int t = (tid >= d) ? part[tid - d] : 0;
        __syncthreads();
        part[tid] += t;
        __syncthreads();
    }
    int run = part[tid] - s;              // exclusive prefix of this chunk
    for (int i = base; i < lim; ++i) {
        off[i] = run; cursor[i] = run; run += deg[i];
    }
    if (tid == 1023) off[NN] = run;       // == 2E
}

__global__ void place_kernel(const int* __restrict__ ei,
                             int* __restrict__ cursor, int* __restrict__ slot) {
    int e = blockIdx.x * blockDim.x + threadIdx.x;
    if (e < NE) {
        int t = ei[NE + e]; int p = atomicAdd(&cursor[t], 1); slot[p] = e;       // fwd id
        int s = ei[e];      int q = atomicAdd(&cursor[s], 1); slot[q] = NE + e;  // bwd id
    }
}

// ===========================================================================
// Edge kernel (CSR path): one wave per original edge, both directions.
// Messages written ONCE, coalesced, bf16. Tension computed inline (fp32).
// ===========================================================================
__global__ __launch_bounds__(1024) void edge_csr_kernel(
    const float* __restrict__ x, const int* __restrict__ ei,
    const float* __restrict__ ea,
    const float* __restrict__ Wm1, const float* __restrict__ bm1,
    const float* __restrict__ Wm2, const float* __restrict__ bm2,
    const float* __restrict__ Wt1, const float* __restrict__ bt1,
    const float* __restrict__ Wt2, const float* __restrict__ bt2,
    __hip_bfloat16* __restrict__ msg, float* __restrict__ e_out)
{
    __shared__ float wm1[72 * 128];
    __shared__ float wm2[128 * 64];
    __shared__ float wt1[64 * 32];
    __shared__ float bm1s[128], bm2s[64], bt1s[32], wt2s[32];

    const int tid = threadIdx.x;
    for (int i = tid; i < 72 * 128; i += 1024) wm1[i] = Wm1[i];
    for (int i = tid; i < 128 * 64; i += 1024) wm2[i] = Wm2[i];
    for (int i = tid; i < 64 * 32; i += 1024) wt1[i] = Wt1[i];
    if (tid < 128) bm1s[tid] = bm1[tid];
    if (tid < 64)  bm2s[tid] = bm2[tid];
    if (tid < 32)  { bt1s[tid] = bt1[tid]; wt2s[tid] = Wt2[tid]; }
    __syncthreads();

    const float bt2v = bt2[0];
    const int lane = tid & 63;
    const int wid  = tid >> 6;
    const int gw   = blockIdx.x * 16 + wid;
    const int nw   = gridDim.x * 16;

    for (int e = gw; e < NE; e += nw) {
        const int s = ei[e];
        const int t = ei[NE + e];
        const float diff = x[t * 64 + lane] - x[s * 64 + lane];
        const float eav  = (lane < 8) ? ea[e * 8 + lane] : 0.f;

        // layer 1 (shared between directions up to sign)
        float z0 = 0.f, z1 = 0.f;
#pragma unroll
        for (int k = 0; k < 64; ++k) {
            const float a = bcastf(diff, k);
            z0 = fmaf(a, wm1[k * 128 + lane], z0);
            z1 = fmaf(a, wm1[k * 128 + 64 + lane], z1);
        }
#pragma unroll
        for (int k = 0; k < 8; ++k) {
            const float a = bcastf(eav, k);
            z0 = fmaf(a, wm1[(64 + k) * 128 + lane], z0);
            z1 = fmaf(a, wm1[(64 + k) * 128 + 64 + lane], z1);
        }
        const float b0 = bm1s[lane], b1 = bm1s[64 + lane];
        const float hf0 = fmaxf(z0 + b0, 0.f), hf1 = fmaxf(z1 + b1, 0.f);
        const float hb0 = fmaxf(b0 - z0, 0.f), hb1 = fmaxf(b1 - z1, 0.f);

        // layer 2
        float mf = 0.f, mb = 0.f;
#pragma unroll
        for (int k = 0; k < 64; ++k) {
            const float w = wm2[k * 64 + lane];
            mf = fmaf(bcastf(hf0, k), w, mf);
            mb = fmaf(bcastf(hb0, k), w, mb);
        }
#pragma unroll
        for (int k = 0; k < 64; ++k) {
            const float w = wm2[(64 + k) * 64 + lane];
            mf = fmaf(bcastf(hf1, k), w, mf);
            mb = fmaf(bcastf(hb1, k), w, mb);
        }
        const float bb = bm2s[lane];
        mf = fmaxf(mf + bb, 0.f);
        mb = fmaxf(mb + bb, 0.f);

        // store messages (coalesced 128B/row, bf16)
        msg[(size_t)e * 64 + lane]        = __float2bfloat16(mf);
        msg[(size_t)(NE + e) * 64 + lane] = __float2bfloat16(mb);

        // tension MLP on m_sym = mf + mb (fp32, in-register)
        const float msym = mf + mb;
        const int j = lane & 31;
        float htv = 0.f;
#pragma unroll
        for (int k = 0; k < 64; ++k) {
            htv = fmaf(bcastf(msym, k), wt1[k * 32 + j], htv);
        }
        htv = fmaxf(htv + bt1s[j], 0.f);
        float p = htv * wt2s[j];
        p += __shfl_xor(p, 1, 64);
        p += __shfl_xor(p, 2, 64);
        p += __shfl_xor(p, 4, 64);
        p += __shfl_xor(p, 8, 64);
        p += __shfl_xor(p, 16, 64);
        if (lane == 0) e_out[e] = p + bt2v;
    }
}

// ===========================================================================
// Node kernel (CSR path): one wave per node; gather own messages, mean,
// then 2-layer update MLP. No atomics.
// ===========================================================================
__global__ __launch_bounds__(1024) void node_csr_kernel(
    const float* __restrict__ x,
    const float* __restrict__ Wu1, const float* __restrict__ bu1,
    const float* __restrict__ Wu2, const float* __restrict__ bu2,
    const __hip_bfloat16* __restrict__ msg,
    const int* __restrict__ off, const int* __restrict__ slot,
    float* __restrict__ x_out)
{
    __shared__ float wu1[128 * 64];
    __shared__ float wu2[64 * 32];
    __shared__ float bu1s[64], bu2s[32];

    const int tid = threadIdx.x;
    for (int i = tid; i < 128 * 64; i += 1024) wu1[i] = Wu1[i];
    for (int i = tid; i < 64 * 32; i += 1024) wu2[i] = Wu2[i];
    if (tid < 64) bu1s[tid] = bu1[tid];
    if (tid < 32) bu2s[tid] = bu2[tid];
    __syncthreads();

    const int lane = tid & 63;
    const int wid  = tid >> 6;
    const int gw   = blockIdx.x * 16 + wid;
    const int nw   = gridDim.x * 16;

    for (int i = gw; i < NN; i += nw) {
        const int b  = off[i];
        const int en = off[i + 1];

        // gather+sum incoming messages; 4-wide unroll for MLP-overlap & MLP
        float a0 = 0.f, a1 = 0.f, a2 = 0.f, a3 = 0.f;
        int k = b;
        for (; k + 4 <= en; k += 4) {
            const int d0 = slot[k], d1 = slot[k + 1], d2 = slot[k + 2], d3 = slot[k + 3];
            a0 += __bfloat162float(msg[(size_t)d0 * 64 + lane]);
            a1 += __bfloat162float(msg[(size_t)d1 * 64 + lane]);
            a2 += __bfloat162float(msg[(size_t)d2 * 64 + lane]);
            a3 += __bfloat162float(msg[(size_t)d3 * 64 + lane]);
        }
        for (; k < en; ++k) {
            const int d = slot[k];
            a0 += __bfloat162float(msg[(size_t)d * 64 + lane]);
        }
        const float inv = 1.f / fmaxf((float)(en - b), 1.f);
        const float av  = ((a0 + a1) + (a2 + a3)) * inv;
        const float xv  = x[i * 64 + lane];

        float z = bu1s[lane];
#pragma unroll
        for (int kk = 0; kk < 64; ++kk) {
            z = fmaf(bcastf(xv, kk), wu1[kk * 64 + lane], z);
        }
#pragma unroll
        for (int kk = 0; kk < 64; ++kk) {
            z = fmaf(bcastf(av, kk), wu1[(64 + kk) * 64 + lane], z);
        }
        const float hu = fmaxf(z, 0.f);

        const int j = lane & 31;
        float o = 0.f;
#pragma unroll
        for (int kk = 0; kk < 64; ++kk) {
            o = fmaf(bcastf(hu, kk), wu2[kk * 32 + j], o);
        }
        if (lane < 32) x_out[i * 32 + j] = o + bu2s[j];
    }
}

// ===========================================================================
// Fallback (round-1 atomic path) — used only if ws_size is too small
// ===========================================================================
__global__ __launch_bounds__(1024) void edge_at_kernel(
    const float* __restrict__ x, const int* __restrict__ ei,
    const float* __restrict__ ea,
    const float* __restrict__ Wm1, const float* __restrict__ bm1,
    const float* __restrict__ Wm2, const float* __restrict__ bm2,
    const float* __restrict__ Wt1, const float* __restrict__ bt1,
    const float* __restrict__ Wt2, const float* __restrict__ bt2,
    float* __restrict__ sums, float* __restrict__ cnt,
    float* __restrict__ e_out)
{
    __shared__ float wm1[72 * 128];
    __shared__ float wm2[128 * 64];
    __shared__ float wt1[64 * 32];
    __shared__ float bm1s[128], bm2s[64], bt1s[32], wt2s[32];
    const int tid = threadIdx.x;
    for (int i = tid; i < 72 * 128; i += 1024) wm1[i] = Wm1[i];
    for (int i = tid; i < 128 * 64; i += 1024) wm2[i] = Wm2[i];
    for (int i = tid; i < 64 * 32; i += 1024) wt1[i] = Wt1[i];
    if (tid < 128) bm1s[tid] = bm1[tid];
    if (tid < 64)  bm2s[tid] = bm2[tid];
    if (tid < 32)  { bt1s[tid] = bt1[tid]; wt2s[tid] = Wt2[tid]; }
    __syncthreads();
    const float bt2v = bt2[0];
    const int lane = tid & 63, wid = tid >> 6;
    const int gw = blockIdx.x * 16 + wid, nw = gridDim.x * 16;
    for (int e = gw; e < NE; e += nw) {
        const int s = ei[e], t = ei[NE + e];
        const float diff = x[t * 64 + lane] - x[s * 64 + lane];
        const float eav = (lane < 8) ? ea[e * 8 + lane] : 0.f;
        float z0 = 0.f, z1 = 0.f;
#pragma unroll
        for (int k = 0; k < 64; ++k) {
            const float a = bcastf(diff, k);
            z0 = fmaf(a, wm1[k * 128 + lane], z0);
            z1 = fmaf(a, wm1[k * 128 + 64 + lane], z1);
        }
#pragma unroll
        for (int k = 0; k < 8; ++k) {
            const float a = bcastf(eav, k);
            z0 = fmaf(a, wm1[(64 + k) * 128 + lane], z0);
            z1 = fmaf(a, wm1[(64 + k) * 128 + 64 + lane], z1);
        }
        const float b0 = bm1s[lane], b1 = bm1s[64 + lane];
        const float hf0 = fmaxf(z0 + b0, 0.f), hf1 = fmaxf(z1 + b1, 0.f);
        const float hb0 = fmaxf(b0 - z0, 0.f), hb1 = fmaxf(b1 - z1, 0.f);
        float mf = 0.f, mb = 0.f;
#pragma unroll
        for (int k = 0; k < 64; ++k) {
            const float w = wm2[k * 64 + lane];
            mf = fmaf(bcastf(hf0, k), w, mf);
            mb = fmaf(bcastf(hb0, k), w, mb);
        }
#pragma unroll
        for (int k = 0; k < 64; ++k) {
            const float w = wm2[(64 + k) * 64 + lane];
            mf = fmaf(bcastf(hf1, k), w, mf);
            mb = fmaf(bcastf(hb1, k), w, mb);
        }
        const float bb = bm2s[lane];
        mf = fmaxf(mf + bb, 0.f);
        mb = fmaxf(mb + bb, 0.f);
        atomicAdd(&sums[t * 64 + lane], mf);
        atomicAdd(&sums[s * 64 + lane], mb);
        if (lane == 0) { atomicAdd(&cnt[t], 1.f); atomicAdd(&cnt[s], 1.f); }
        const float msym = mf + mb;
        const int j = lane & 31;
        float htv = 0.f;
#pragma unroll
        for (int k = 0; k < 64; ++k) htv = fmaf(bcastf(msym, k), wt1[k * 32 + j], htv);
        htv = fmaxf(htv + bt1s[j], 0.f);
        float p = htv * wt2s[j];
        p += __shfl_xor(p, 1, 64); p += __shfl_xor(p, 2, 64); p += __shfl_xor(p, 4, 64);
        p += __shfl_xor(p, 8, 64); p += __shfl_xor(p, 16, 64);
        if (lane == 0) e_out[e] = p + bt2v;
    }
}

__global__ __launch_bounds__(1024) void node_at_kernel(
    const float* __restrict__ x,
    const float* __restrict__ Wu1, const float* __restrict__ bu1,
    const float* __restrict__ Wu2, const float* __restrict__ bu2,
    const float* __restrict__ sums, const float* __restrict__ cnt,
    float* __restrict__ x_out)
{
    __shared__ float wu1[128 * 64];
    __shared__ float wu2[64 * 32];
    __shared__ float bu1s[64], bu2s[32];
    const int tid = threadIdx.x;
    for (int i = tid; i < 128 * 64; i += 1024) wu1[i] = Wu1[i];
    for (int i = tid; i < 64 * 32; i += 1024) wu2[i] = Wu2[i];
    if (tid < 64) bu1s[tid] = bu1[tid];
    if (tid < 32) bu2s[tid] = bu2[tid];
    __syncthreads();
    const int lane = tid & 63, wid = tid >> 6;
    const int gw = blockIdx.x * 16 + wid, nw = gridDim.x * 16;
    for (int i = gw; i < NN; i += nw) {
        const float xv = x[i * 64 + lane];
        const float inv = 1.f / fmaxf(cnt[i], 1.f);
        const float av = sums[i * 64 + lane] * inv;
        float z = bu1s[lane];
#pragma unroll
        for (int k = 0; k < 64; ++k) z = fmaf(bcastf(xv, k), wu1[k * 64 + lane], z);
#pragma unroll
        for (int k = 0; k < 64; ++k) z = fmaf(bcastf(av, k), wu1[(64 + k) * 64 + lane], z);
        const float hu = fmaxf(z, 0.f);
        const int j = lane & 31;
        float o = 0.f;
#pragma unroll
        for (int k = 0; k < 64; ++k) o = fmaf(bcastf(hu, k), wu2[k * 32 + j], o);
        if (lane < 32) x_out[i * 32 + j] = o + bu2s[j];
    }
}

extern "C" void kernel_launch(void* const* d_in, const int* in_sizes, int n_in,
                              void* d_out, int out_size, void* d_ws, size_t ws_size,
                              hipStream_t stream) {
    const float* x   = (const float*)d_in[0];
    const int*   ei  = (const int*)d_in[1];
    const float* ea  = (const float*)d_in[2];
    const float* Wm1 = (const float*)d_in[3];
    const float* bm1 = (const float*)d_in[4];
    const float* Wm2 = (const float*)d_in[5];
    const float* bm2 = (const float*)d_in[6];
    const float* Wu1 = (const float*)d_in[7];
    const float* bu1 = (const float*)d_in[8];
    const float* Wu2 = (const float*)d_in[9];
    const float* bu2 = (const float*)d_in[10];
    const float* Wt1 = (const float*)d_in[11];
    const float* bt1 = (const float*)d_in[12];
    const float* Wt2 = (const float*)d_in[13];
    const float* bt2 = (const float*)d_in[14];

    float* x_out = (float*)d_out;
    float* e_out = x_out + (size_t)NN * 32;

    const size_t msg_bytes  = (size_t)2 * NE * 64 * sizeof(__hip_bfloat16); // 128 MB
    const size_t slot_bytes = (size_t)2 * NE * sizeof(int);                 //   4 MB
    const size_t int_bytes  = (size_t)(NN + NN + 1 + NN) * sizeof(int);     // ~600 KB
    const size_t need = msg_bytes + slot_bytes + int_bytes;

    if (ws_size >= need) {
        __hip_bfloat16* msg = (__hip_bfloat16*)d_ws;
        int* slot   = (int*)((char*)d_ws + msg_bytes);
        int* deg    = slot + (size_t)2 * NE;
        int* off    = deg + NN;
        int* cursor = off + NN + 1;

        hipMemsetAsync(deg, 0, (size_t)NN * sizeof(int), stream);
        hist_kernel<<<(NE + 1023) / 1024, 1024, 0, stream>>>(ei, deg);
        scan_kernel<<<1, 1024, 0, stream>>>(deg, off, cursor);
        place_kernel<<<(NE + 1023) / 1024, 1024, 0, stream>>>(ei, cursor, slot);
        edge_csr_kernel<<<512, 1024, 0, stream>>>(x, ei, ea, Wm1, bm1, Wm2, bm2,
                                                  Wt1, bt1, Wt2, bt2, msg, e_out);
        node_csr_kernel<<<256, 1024, 0, stream>>>(x, Wu1, bu1, Wu2, bu2,
                                                  msg, off, slot, x_out);
    } else {
        // fallback: round-1 atomic path (ws too small for CSR + messages)
        float* sums = (float*)d_ws;
        float* cnt  = sums + (size_t)NN * 64;
        hipMemsetAsync(d_ws, 0, ((size_t)NN * 64 + NN) * sizeof(float), stream);
        edge_at_kernel<<<512, 1024, 0, stream>>>(x, ei, ea, Wm1, bm1, Wm2, bm2,
                                                 Wt1, bt1, Wt2, bt2, sums, cnt, e_out);
        node_at_kernel<<<256, 1024, 0, stream>>>(x, Wu1, bu1, Wu2, bu2, sums, cnt, x_out);
    }
}

// Round 3
// 772.702 us; speedup vs baseline: 12.7551x; 9.0243x over previous
//
#include <hip/hip_runtime.h>
#include <hip/hip_bf16.h>

// Problem constants (match reference)
#define NN 50000
#define NE 500000
// D_NODE=64, D_EDGE=8, D_MSG=64, H_MSG=128, H_UPD=64, H_TEN=32, D_OUT=32

typedef _Float16 half8 __attribute__((ext_vector_type(8)));
typedef float f32x4 __attribute__((ext_vector_type(4)));

#define MFMA16(a, b, c) __builtin_amdgcn_mfma_f32_16x16x32_f16(a, b, c, 0, 0, 0)

__device__ __forceinline__ float h2f(unsigned short b) {
    return (float)__builtin_bit_cast(_Float16, b);
}

// ===========================================================================
// CSR-build kernels (directed edge d in [0,2E): d<NE fwd tgt=ei[NE+d];
//                    d>=NE bwd tgt=ei[d-NE])
// ===========================================================================
__global__ void hist_kernel(const int* __restrict__ ei, int* __restrict__ deg) {
    int e = blockIdx.x * blockDim.x + threadIdx.x;
    if (e < NE) {
        atomicAdd(&deg[ei[NE + e]], 1);   // fwd message targets t
        atomicAdd(&deg[ei[e]], 1);        // bwd message targets s
    }
}

__global__ __launch_bounds__(1024) void scan_kernel(
    const int* __restrict__ deg, int* __restrict__ off, int* __restrict__ cursor) {
    __shared__ int part[1024];
    const int C = (NN + 1023) / 1024;
    const int tid = threadIdx.x;
    const int base = tid * C;
    const int lim = min(base + C, NN);
    int s = 0;
    for (int i = base; i < lim; ++i) s += deg[i];
    part[tid] = s;
    __syncthreads();
    for (int d = 1; d < 1024; d <<= 1) {
        int t = (tid >= d) ? part[tid - d] : 0;
        __syncthreads();
        part[tid] += t;
        __syncthreads();
    }
    int run = part[tid] - s;
    for (int i = base; i < lim; ++i) {
        off[i] = run; cursor[i] = run; run += deg[i];
    }
    if (tid == 1023) off[NN] = run;
}

__global__ void place_kernel(const int* __restrict__ ei,
                             int* __restrict__ cursor, int* __restrict__ slot) {
    int e = blockIdx.x * blockDim.x + threadIdx.x;
    if (e < NE) {
        int t = ei[NE + e]; int p = atomicAdd(&cursor[t], 1); slot[p] = e;
        int s = ei[e];      int q = atomicAdd(&cursor[s], 1); slot[q] = NE + e;
    }
}

// ===========================================================================
// Edge kernel (MFMA): 4 waves/block, each wave owns batches of 16 edge-pairs.
// A-frag layout assumed: lane l holds A[row=l&15][k=(l>>4)*8+i], i=0..7
// B-frag layout: lane l holds B[k=(l>>4)*8+i][col=l&15]
// C/D layout (verified): lane l holds D[row=(l>>4)*4+r][col=l&15]
// ===========================================================================
#define SW 136   // scratch row stride in halfs (272 B, 16B-aligned rows)

__global__ __launch_bounds__(256) void edge_mfma_kernel(
    const float* __restrict__ x, const int* __restrict__ ei,
    const float* __restrict__ ea,
    const float* __restrict__ Wm1, const float* __restrict__ bm1,
    const float* __restrict__ Wm2, const float* __restrict__ bm2,
    const float* __restrict__ Wt1, const float* __restrict__ bt1,
    const float* __restrict__ Wt2, const float* __restrict__ bt2,
    _Float16* __restrict__ msg, float* __restrict__ e_out)
{
    // Pre-swizzled weight fragments in LDS (f16):
    __shared__ __align__(16) _Float16 wm1_sw[3 * 8 * 64 * 8];   // 24 KB [kt3][nt8][l][8]
    __shared__ __align__(16) _Float16 wm2_sw[4 * 4 * 64 * 8];   // 16 KB [kt4][nt4][l][8]
    __shared__ __align__(16) _Float16 wt1_sw[2 * 2 * 64 * 8];   //  4 KB [jt2][kt2][l][8]
    __shared__ __align__(16) _Float16 hscr[4 * 16 * SW];        // 17 KB per-wave scratch

    const int tid = threadIdx.x;
    for (int idx = tid; idx < 12288; idx += 256) {   // Wm1 [72,128] pad K->96
        int i = idx & 7, l = (idx >> 3) & 63, nt = (idx >> 9) & 7, kt = idx >> 12;
        int k = kt * 32 + ((l >> 4) << 3) + i, n = nt * 16 + (l & 15);
        wm1_sw[idx] = (k < 72) ? (_Float16)Wm1[k * 128 + n] : (_Float16)0.f;
    }
    for (int idx = tid; idx < 8192; idx += 256) {    // Wm2 [128,64]
        int i = idx & 7, l = (idx >> 3) & 63, nt = (idx >> 9) & 3, kt = idx >> 11;
        int k = kt * 32 + ((l >> 4) << 3) + i, n = nt * 16 + (l & 15);
        wm2_sw[idx] = (_Float16)Wm2[k * 64 + n];
    }
    for (int idx = tid; idx < 2048; idx += 256) {    // Wt1^T as A-frags [32,64]
        int i = idx & 7, l = (idx >> 3) & 63, kt = (idx >> 9) & 1, jt = idx >> 10;
        int k = kt * 32 + ((l >> 4) << 3) + i, j = jt * 16 + (l & 15);
        wt1_sw[idx] = (_Float16)Wt1[k * 32 + j];
    }
    __syncthreads();

    const int lane = tid & 63;
    const int g = lane >> 4;          // k-group / row-group
    const int c = lane & 15;          // column (or row for A-frags)
    const int wid = tid >> 6;
    _Float16* hs = &hscr[wid * 16 * SW];

    // per-lane bias registers
    float bm1v[8], bm2v[4], bt1v[8], wt2v[8];
#pragma unroll
    for (int nt = 0; nt < 8; ++nt) bm1v[nt] = bm1[nt * 16 + c];
#pragma unroll
    for (int nt = 0; nt < 4; ++nt) bm2v[nt] = bm2[nt * 16 + c];
#pragma unroll
    for (int jt = 0; jt < 2; ++jt)
#pragma unroll
        for (int r = 0; r < 4; ++r) {
            int j = jt * 16 + g * 4 + r;
            bt1v[jt * 4 + r] = bt1[j];
            wt2v[jt * 4 + r] = Wt2[j];
        }
    const float bt2v = bt2[0];

    const float4* xp = (const float4*)x;
    const float4* eap = (const float4*)ea;

    const int gwave = blockIdx.x * 4 + wid;
    const int nwave = gridDim.x * 4;
    const int NB = NE / 16;   // 31250 exact

    for (int bt = gwave; bt < NB; bt += nwave) {
        const int eb = bt * 16;
        const int e = eb + c;                 // this lane's row-edge
        const int sv = ei[e];
        const int tv = ei[NE + e];

        // ---- build A1 fragments (diff in k<64, ea in k=64..71, pad 0) ----
        half8 a0, a1, a2;
        {
            float4 t0 = xp[(size_t)tv * 16 + g * 2];
            float4 t1 = xp[(size_t)tv * 16 + g * 2 + 1];
            float4 s0 = xp[(size_t)sv * 16 + g * 2];
            float4 s1 = xp[(size_t)sv * 16 + g * 2 + 1];
            a0[0] = (_Float16)(t0.x - s0.x); a0[1] = (_Float16)(t0.y - s0.y);
            a0[2] = (_Float16)(t0.z - s0.z); a0[3] = (_Float16)(t0.w - s0.w);
            a0[4] = (_Float16)(t1.x - s1.x); a0[5] = (_Float16)(t1.y - s1.y);
            a0[6] = (_Float16)(t1.z - s1.z); a0[7] = (_Float16)(t1.w - s1.w);
            float4 t2 = xp[(size_t)tv * 16 + 8 + g * 2];
            float4 t3 = xp[(size_t)tv * 16 + 8 + g * 2 + 1];
            float4 s2 = xp[(size_t)sv * 16 + 8 + g * 2];
            float4 s3 = xp[(size_t)sv * 16 + 8 + g * 2 + 1];
            a1[0] = (_Float16)(t2.x - s2.x); a1[1] = (_Float16)(t2.y - s2.y);
            a1[2] = (_Float16)(t2.z - s2.z); a1[3] = (_Float16)(t2.w - s2.w);
            a1[4] = (_Float16)(t3.x - s3.x); a1[5] = (_Float16)(t3.y - s3.y);
            a1[6] = (_Float16)(t3.z - s3.z); a1[7] = (_Float16)(t3.w - s3.w);
        }
        a2 = (half8)(_Float16)0.f;
        if (g == 0) {
            float4 e0 = eap[(size_t)e * 2];
            float4 e1 = eap[(size_t)e * 2 + 1];
            a2[0] = (_Float16)e0.x; a2[1] = (_Float16)e0.y;
            a2[2] = (_Float16)e0.z; a2[3] = (_Float16)e0.w;
            a2[4] = (_Float16)e1.x; a2[5] = (_Float16)e1.y;
            a2[6] = (_Float16)e1.z; a2[7] = (_Float16)e1.w;
        }

        // ---- layer 1: Z[16,128] = A1[16,96] @ Wm1 ----
        f32x4 z[8];
#pragma unroll
        for (int nt = 0; nt < 8; ++nt) z[nt] = (f32x4)0.f;
#pragma unroll
        for (int nt = 0; nt < 8; ++nt) {
            z[nt] = MFMA16(a0, *(const half8*)&wm1_sw[((0 * 8 + nt) * 64 + lane) * 8], z[nt]);
            z[nt] = MFMA16(a1, *(const half8*)&wm1_sw[((1 * 8 + nt) * 64 + lane) * 8], z[nt]);
            z[nt] = MFMA16(a2, *(const half8*)&wm1_sw[((2 * 8 + nt) * 64 + lane) * 8], z[nt]);
        }

        // ---- hf = relu(z+b) -> scratch -> A-frags; layer2 fwd ----
#pragma unroll
        for (int nt = 0; nt < 8; ++nt)
#pragma unroll
            for (int r = 0; r < 4; ++r)
                hs[(g * 4 + r) * SW + nt * 16 + c] = (_Float16)fmaxf(z[nt][r] + bm1v[nt], 0.f);
        half8 hA[4];
#pragma unroll
        for (int kt = 0; kt < 4; ++kt)
            hA[kt] = *(const half8*)&hs[c * SW + kt * 32 + g * 8];
        f32x4 m_f[4];
#pragma unroll
        for (int nt = 0; nt < 4; ++nt) m_f[nt] = (f32x4)0.f;
#pragma unroll
        for (int kt = 0; kt < 4; ++kt)
#pragma unroll
            for (int nt = 0; nt < 4; ++nt)
                m_f[nt] = MFMA16(hA[kt], *(const half8*)&wm2_sw[((kt * 4 + nt) * 64 + lane) * 8], m_f[nt]);

        // ---- hb = relu(b-z) -> scratch -> A-frags; layer2 bwd ----
#pragma unroll
        for (int nt = 0; nt < 8; ++nt)
#pragma unroll
            for (int r = 0; r < 4; ++r)
                hs[(g * 4 + r) * SW + nt * 16 + c] = (_Float16)fmaxf(bm1v[nt] - z[nt][r], 0.f);
#pragma unroll
        for (int kt = 0; kt < 4; ++kt)
            hA[kt] = *(const half8*)&hs[c * SW + kt * 32 + g * 8];
        f32x4 m_b[4];
#pragma unroll
        for (int nt = 0; nt < 4; ++nt) m_b[nt] = (f32x4)0.f;
#pragma unroll
        for (int kt = 0; kt < 4; ++kt)
#pragma unroll
            for (int nt = 0; nt < 4; ++nt)
                m_b[nt] = MFMA16(hA[kt], *(const half8*)&wm2_sw[((kt * 4 + nt) * 64 + lane) * 8], m_b[nt]);

        // ---- bias+relu, store msg, write m_sym scratch ----
#pragma unroll
        for (int nt = 0; nt < 4; ++nt)
#pragma unroll
            for (int r = 0; r < 4; ++r) {
                float mfv = fmaxf(m_f[nt][r] + bm2v[nt], 0.f);
                float mbv = fmaxf(m_b[nt][r] + bm2v[nt], 0.f);
                int row = g * 4 + r, col = nt * 16 + c;
                msg[(size_t)(eb + row) * 64 + col] = (_Float16)mfv;
                msg[(size_t)(NE + eb + row) * 64 + col] = (_Float16)mbv;
                hs[row * SW + col] = (_Float16)(mfv + mbv);
            }

        // ---- tension: D'[j, e] = Wt1^T @ m_sym^T (B-frag == A-frag addressing) ----
        half8 mB[2];
#pragma unroll
        for (int kt = 0; kt < 2; ++kt)
            mB[kt] = *(const half8*)&hs[c * SW + kt * 32 + g * 8];
        f32x4 ct[2];
        ct[0] = (f32x4)0.f; ct[1] = (f32x4)0.f;
#pragma unroll
        for (int jt = 0; jt < 2; ++jt)
#pragma unroll
            for (int kt = 0; kt < 2; ++kt)
                ct[jt] = MFMA16(*(const half8*)&wt1_sw[((jt * 2 + kt) * 64 + lane) * 8], mB[kt], ct[jt]);
        float p = 0.f;
#pragma unroll
        for (int jt = 0; jt < 2; ++jt)
#pragma unroll
            for (int r = 0; r < 4; ++r)
                p += fmaxf(ct[jt][r] + bt1v[jt * 4 + r], 0.f) * wt2v[jt * 4 + r];
        p += __shfl_xor(p, 16);
        p += __shfl_xor(p, 32);
        if (lane < 16) e_out[eb + c] = p + bt2v;
    }
}

// ===========================================================================
// Node kernel (MFMA): 4 waves/block, batches of 16 nodes per wave.
// gather(mean) -> [x|aggr][16,128] @ Wu1 -> relu -> @ Wu2 (transposed trick)
// ===========================================================================
#define SWN 72   // node scratch row stride in halfs (144 B)

__global__ __launch_bounds__(256) void node_mfma_kernel(
    const float* __restrict__ x,
    const float* __restrict__ Wu1, const float* __restrict__ bu1,
    const float* __restrict__ Wu2, const float* __restrict__ bu2,
    const _Float16* __restrict__ msg,
    const int* __restrict__ off, const int* __restrict__ slot,
    float* __restrict__ x_out)
{
    __shared__ __align__(16) _Float16 wu1_sw[4 * 4 * 64 * 8];   // 16 KB
    __shared__ __align__(16) _Float16 wu2_sw[2 * 2 * 64 * 8];   //  4 KB [jt2][kt2]
    __shared__ __align__(16) _Float16 nscr[4 * 16 * SWN];       //  9 KB

    const int tid = threadIdx.x;
    for (int idx = tid; idx < 8192; idx += 256) {    // Wu1 [128,64]
        int i = idx & 7, l = (idx >> 3) & 63, nt = (idx >> 9) & 3, kt = idx >> 11;
        int k = kt * 32 + ((l >> 4) << 3) + i, n = nt * 16 + (l & 15);
        wu1_sw[idx] = (_Float16)Wu1[k * 64 + n];
    }
    for (int idx = tid; idx < 2048; idx += 256) {    // Wu2^T as A-frags [32,64]
        int i = idx & 7, l = (idx >> 3) & 63, kt = (idx >> 9) & 1, jt = idx >> 10;
        int k = kt * 32 + ((l >> 4) << 3) + i, j = jt * 16 + (l & 15);
        wu2_sw[idx] = (_Float16)Wu2[k * 32 + j];
    }
    __syncthreads();

    const int lane = tid & 63;
    const int g = lane >> 4;
    const int c = lane & 15;
    const int wid = tid >> 6;
    _Float16* ns = &nscr[wid * 16 * SWN];
    unsigned int* ns_u32 = (unsigned int*)ns;

    float bu1v[4], bu2v[8];
#pragma unroll
    for (int nt = 0; nt < 4; ++nt) bu1v[nt] = bu1[nt * 16 + c];
#pragma unroll
    for (int jt = 0; jt < 2; ++jt)
#pragma unroll
        for (int r = 0; r < 4; ++r) bu2v[jt * 4 + r] = bu2[jt * 16 + g * 4 + r];

    const float4* xp = (const float4*)x;
    const unsigned int* msg_u32 = (const unsigned int*)msg;

    const int gwave = blockIdx.x * 4 + wid;
    const int nwave = gridDim.x * 4;
    const int NB = NN / 16;   // 3125 exact

    for (int bt = gwave; bt < NB; bt += nwave) {
        const int nbase = bt * 16;

        // ---- gather + mean -> aggr scratch (f16 packed dwords) ----
        for (int j = 0; j < 16; ++j) {
            const int n = nbase + j;
            const int b = off[n], en = off[n + 1];
            float acc0 = 0.f, acc1 = 0.f;
            for (int it = b + (lane >> 5); it < en; it += 2) {
                const int row = slot[it];
                const unsigned int d = msg_u32[(size_t)row * 32 + (lane & 31)];
                acc0 += h2f((unsigned short)(d & 0xffffu));
                acc1 += h2f((unsigned short)(d >> 16));
            }
            acc0 += __shfl_xor(acc0, 32);
            acc1 += __shfl_xor(acc1, 32);
            const float inv = 1.f / fmaxf((float)(en - b), 1.f);
            if (lane < 32) {
                unsigned short lo = __builtin_bit_cast(unsigned short, (_Float16)(acc0 * inv));
                unsigned short hi = __builtin_bit_cast(unsigned short, (_Float16)(acc1 * inv));
                ns_u32[j * (SWN / 2) + lane] = (unsigned int)lo | ((unsigned int)hi << 16);
            }
        }

        // ---- A frags: kt0,1 from x (global), kt2,3 from aggr scratch ----
        const int nn_ = nbase + c;
        half8 af[4];
        {
            float4 x0 = xp[(size_t)nn_ * 16 + g * 2];
            float4 x1 = xp[(size_t)nn_ * 16 + g * 2 + 1];
            af[0][0] = (_Float16)x0.x; af[0][1] = (_Float16)x0.y;
            af[0][2] = (_Float16)x0.z; af[0][3] = (_Float16)x0.w;
            af[0][4] = (_Float16)x1.x; af[0][5] = (_Float16)x1.y;
            af[0][6] = (_Float16)x1.z; af[0][7] = (_Float16)x1.w;
            float4 x2 = xp[(size_t)nn_ * 16 + 8 + g * 2];
            float4 x3 = xp[(size_t)nn_ * 16 + 8 + g * 2 + 1];
            af[1][0] = (_Float16)x2.x; af[1][1] = (_Float16)x2.y;
            af[1][2] = (_Float16)x2.z; af[1][3] = (_Float16)x2.w;
            af[1][4] = (_Float16)x3.x; af[1][5] = (_Float16)x3.y;
            af[1][6] = (_Float16)x3.z; af[1][7] = (_Float16)x3.w;
        }
        af[2] = *(const half8*)&ns[c * SWN + 0 * 32 + g * 8];
        af[3] = *(const half8*)&ns[c * SWN + 1 * 32 + g * 8];

        // ---- layer u1 ----
        f32x4 hu[4];
#pragma unroll
        for (int nt = 0; nt < 4; ++nt) hu[nt] = (f32x4)0.f;
#pragma unroll
        for (int kt = 0; kt < 4; ++kt)
#pragma unroll
            for (int nt = 0; nt < 4; ++nt)
                hu[nt] = MFMA16(af[kt], *(const half8*)&wu1_sw[((kt * 4 + nt) * 64 + lane) * 8], hu[nt]);

        // ---- relu -> scratch (reuse) ----
#pragma unroll
        for (int nt = 0; nt < 4; ++nt)
#pragma unroll
            for (int r = 0; r < 4; ++r)
                ns[(g * 4 + r) * SWN + nt * 16 + c] = (_Float16)fmaxf(hu[nt][r] + bu1v[nt], 0.f);

        // ---- layer u2 (transposed trick): D'[j, node] ----
        half8 hB[2];
#pragma unroll
        for (int kt = 0; kt < 2; ++kt)
            hB[kt] = *(const half8*)&ns[c * SWN + kt * 32 + g * 8];
        f32x4 co[2];
        co[0] = (f32x4)0.f; co[1] = (f32x4)0.f;
#pragma unroll
        for (int jt = 0; jt < 2; ++jt)
#pragma unroll
            for (int kt = 0; kt < 2; ++kt)
                co[jt] = MFMA16(*(const half8*)&wu2_sw[((jt * 2 + kt) * 64 + lane) * 8], hB[kt], co[jt]);

        // ---- store x_out[node, j] ----
#pragma unroll
        for (int jt = 0; jt < 2; ++jt)
#pragma unroll
            for (int r = 0; r < 4; ++r)
                x_out[(size_t)(nbase + c) * 32 + jt * 16 + g * 4 + r] = co[jt][r] + bu2v[jt * 4 + r];
    }
}

extern "C" void kernel_launch(void* const* d_in, const int* in_sizes, int n_in,
                              void* d_out, int out_size, void* d_ws, size_t ws_size,
                              hipStream_t stream) {
    const float* x   = (const float*)d_in[0];
    const int*   ei  = (const int*)d_in[1];
    const float* ea  = (const float*)d_in[2];
    const float* Wm1 = (const float*)d_in[3];
    const float* bm1 = (const float*)d_in[4];
    const float* Wm2 = (const float*)d_in[5];
    const float* bm2 = (const float*)d_in[6];
    const float* Wu1 = (const float*)d_in[7];
    const float* bu1 = (const float*)d_in[8];
    const float* Wu2 = (const float*)d_in[9];
    const float* bu2 = (const float*)d_in[10];
    const float* Wt1 = (const float*)d_in[11];
    const float* bt1 = (const float*)d_in[12];
    const float* Wt2 = (const float*)d_in[13];
    const float* bt2 = (const float*)d_in[14];

    float* x_out = (float*)d_out;
    float* e_out = x_out + (size_t)NN * 32;

    const size_t msg_bytes = (size_t)2 * NE * 64 * sizeof(_Float16); // 128 MB
    _Float16* msg = (_Float16*)d_ws;
    int* slot   = (int*)((char*)d_ws + msg_bytes);
    int* deg    = slot + (size_t)2 * NE;
    int* off    = deg + NN;
    int* cursor = off + NN + 1;

    hipMemsetAsync(deg, 0, (size_t)NN * sizeof(int), stream);
    hist_kernel<<<(NE + 1023) / 1024, 1024, 0, stream>>>(ei, deg);
    scan_kernel<<<1, 1024, 0, stream>>>(deg, off, cursor);
    place_kernel<<<(NE + 1023) / 1024, 1024, 0, stream>>>(ei, cursor, slot);

    edge_mfma_kernel<<<512, 256, 0, stream>>>(x, ei, ea, Wm1, bm1, Wm2, bm2,
                                              Wt1, bt1, Wt2, bt2, msg, e_out);
    node_mfma_kernel<<<256, 256, 0, stream>>>(x, Wu1, bu1, Wu2, bu2,
                                              msg, off, slot, x_out);
}

// Round 4
// 439.953 us; speedup vs baseline: 22.4023x; 1.7563x over previous
//
#include <hip/hip_runtime.h>
#include <hip/hip_bf16.h>

// Problem constants (match reference)
#define NN 50000
#define NE 500000
// D_NODE=64, D_EDGE=8, D_MSG=64, H_MSG=128, H_UPD=64, H_TEN=32, D_OUT=32

typedef _Float16 half8 __attribute__((ext_vector_type(8)));
typedef float f32x4 __attribute__((ext_vector_type(4)));

#define MFMA16(a, b, c) __builtin_amdgcn_mfma_f32_16x16x32_f16(a, b, c, 0, 0, 0)

__device__ __forceinline__ float h2f(unsigned short b) {
    return (float)__builtin_bit_cast(_Float16, b);
}

// ===========================================================================
// CSR-build kernels (directed edge d in [0,2E): d<NE fwd tgt=ei[NE+d];
//                    d>=NE bwd tgt=ei[d-NE])
// ===========================================================================
__global__ void hist_kernel(const int* __restrict__ ei, int* __restrict__ deg) {
    int e = blockIdx.x * blockDim.x + threadIdx.x;
    if (e < NE) {
        atomicAdd(&deg[ei[NE + e]], 1);   // fwd message targets t
        atomicAdd(&deg[ei[e]], 1);        // bwd message targets s
    }
}

__global__ __launch_bounds__(1024) void scan_kernel(
    const int* __restrict__ deg, int* __restrict__ off, int* __restrict__ cursor) {
    __shared__ int part[1024];
    const int C = (NN + 1023) / 1024;
    const int tid = threadIdx.x;
    const int base = tid * C;
    const int lim = min(base + C, NN);
    int s = 0;
    for (int i = base; i < lim; ++i) s += deg[i];
    part[tid] = s;
    __syncthreads();
    for (int d = 1; d < 1024; d <<= 1) {
        int t = (tid >= d) ? part[tid - d] : 0;
        __syncthreads();
        part[tid] += t;
        __syncthreads();
    }
    int run = part[tid] - s;
    for (int i = base; i < lim; ++i) {
        off[i] = run; cursor[i] = run; run += deg[i];
    }
    if (tid == 1023) off[NN] = run;
}

__global__ void place_kernel(const int* __restrict__ ei,
                             int* __restrict__ cursor, int* __restrict__ slot) {
    int e = blockIdx.x * blockDim.x + threadIdx.x;
    if (e < NE) {
        int t = ei[NE + e]; int p = atomicAdd(&cursor[t], 1); slot[p] = e;
        int s = ei[e];      int q = atomicAdd(&cursor[s], 1); slot[q] = NE + e;
    }
}

// ===========================================================================
// Edge kernel (MFMA): 8 waves/block (512 thr), each wave owns batches of 16
// edge-pairs. Layouts verified in round 3:
//   A-frag: lane l holds A[row=l&15][k=(l>>4)*8+i]
//   B-frag: lane l holds B[k=(l>>4)*8+i][col=l&15]
//   C/D   : lane l holds D[row=(l>>4)*4+r][col=l&15]
// ===========================================================================
#define SW 136   // scratch row stride in halfs (272 B, 16B-aligned rows)
#define EW 8     // waves per block

__global__ __launch_bounds__(512) void edge_mfma_kernel(
    const float* __restrict__ x, const int* __restrict__ ei,
    const float* __restrict__ ea,
    const float* __restrict__ Wm1, const float* __restrict__ bm1,
    const float* __restrict__ Wm2, const float* __restrict__ bm2,
    const float* __restrict__ Wt1, const float* __restrict__ bt1,
    const float* __restrict__ Wt2, const float* __restrict__ bt2,
    _Float16* __restrict__ msg, float* __restrict__ e_out)
{
    __shared__ __align__(16) _Float16 wm1_sw[3 * 8 * 64 * 8];   // 24 KB
    __shared__ __align__(16) _Float16 wm2_sw[4 * 4 * 64 * 8];   // 16 KB
    __shared__ __align__(16) _Float16 wt1_sw[2 * 2 * 64 * 8];   //  4 KB
    __shared__ __align__(16) _Float16 hscr[EW * 16 * SW];       // 34 KB

    const int tid = threadIdx.x;
    for (int idx = tid; idx < 12288; idx += 512) {   // Wm1 [72,128] pad K->96
        int i = idx & 7, l = (idx >> 3) & 63, nt = (idx >> 9) & 7, kt = idx >> 12;
        int k = kt * 32 + ((l >> 4) << 3) + i, n = nt * 16 + (l & 15);
        wm1_sw[idx] = (k < 72) ? (_Float16)Wm1[k * 128 + n] : (_Float16)0.f;
    }
    for (int idx = tid; idx < 8192; idx += 512) {    // Wm2 [128,64]
        int i = idx & 7, l = (idx >> 3) & 63, nt = (idx >> 9) & 3, kt = idx >> 11;
        int k = kt * 32 + ((l >> 4) << 3) + i, n = nt * 16 + (l & 15);
        wm2_sw[idx] = (_Float16)Wm2[k * 64 + n];
    }
    for (int idx = tid; idx < 2048; idx += 512) {    // Wt1^T as A-frags [32,64]
        int i = idx & 7, l = (idx >> 3) & 63, kt = (idx >> 9) & 1, jt = idx >> 10;
        int k = kt * 32 + ((l >> 4) << 3) + i, j = jt * 16 + (l & 15);
        wt1_sw[idx] = (_Float16)Wt1[k * 32 + j];
    }
    __syncthreads();

    const int lane = tid & 63;
    const int g = lane >> 4;
    const int c = lane & 15;
    const int wid = tid >> 6;
    _Float16* hs = &hscr[wid * 16 * SW];

    float bm1v[8], bm2v[4], bt1v[8], wt2v[8];
#pragma unroll
    for (int nt = 0; nt < 8; ++nt) bm1v[nt] = bm1[nt * 16 + c];
#pragma unroll
    for (int nt = 0; nt < 4; ++nt) bm2v[nt] = bm2[nt * 16 + c];
#pragma unroll
    for (int jt = 0; jt < 2; ++jt)
#pragma unroll
        for (int r = 0; r < 4; ++r) {
            int j = jt * 16 + g * 4 + r;
            bt1v[jt * 4 + r] = bt1[j];
            wt2v[jt * 4 + r] = Wt2[j];
        }
    const float bt2v = bt2[0];

    const float4* xp = (const float4*)x;
    const float4* eap = (const float4*)ea;

    const int gwave = blockIdx.x * EW + wid;
    const int nwave = gridDim.x * EW;
    const int NB = NE / 16;   // 31250 exact

    for (int bt = gwave; bt < NB; bt += nwave) {
        const int eb = bt * 16;
        const int e = eb + c;
        const int sv = ei[e];
        const int tv = ei[NE + e];

        // ---- build A1 fragments (diff in k<64, ea in k=64..71, pad 0) ----
        half8 a0, a1, a2;
        {
            float4 t0 = xp[(size_t)tv * 16 + g * 2];
            float4 t1 = xp[(size_t)tv * 16 + g * 2 + 1];
            float4 s0 = xp[(size_t)sv * 16 + g * 2];
            float4 s1 = xp[(size_t)sv * 16 + g * 2 + 1];
            a0[0] = (_Float16)(t0.x - s0.x); a0[1] = (_Float16)(t0.y - s0.y);
            a0[2] = (_Float16)(t0.z - s0.z); a0[3] = (_Float16)(t0.w - s0.w);
            a0[4] = (_Float16)(t1.x - s1.x); a0[5] = (_Float16)(t1.y - s1.y);
            a0[6] = (_Float16)(t1.z - s1.z); a0[7] = (_Float16)(t1.w - s1.w);
            float4 t2 = xp[(size_t)tv * 16 + 8 + g * 2];
            float4 t3 = xp[(size_t)tv * 16 + 8 + g * 2 + 1];
            float4 s2 = xp[(size_t)sv * 16 + 8 + g * 2];
            float4 s3 = xp[(size_t)sv * 16 + 8 + g * 2 + 1];
            a1[0] = (_Float16)(t2.x - s2.x); a1[1] = (_Float16)(t2.y - s2.y);
            a1[2] = (_Float16)(t2.z - s2.z); a1[3] = (_Float16)(t2.w - s2.w);
            a1[4] = (_Float16)(t3.x - s3.x); a1[5] = (_Float16)(t3.y - s3.y);
            a1[6] = (_Float16)(t3.z - s3.z); a1[7] = (_Float16)(t3.w - s3.w);
        }
        a2 = (half8)(_Float16)0.f;
        if (g == 0) {
            float4 e0 = eap[(size_t)e * 2];
            float4 e1 = eap[(size_t)e * 2 + 1];
            a2[0] = (_Float16)e0.x; a2[1] = (_Float16)e0.y;
            a2[2] = (_Float16)e0.z; a2[3] = (_Float16)e0.w;
            a2[4] = (_Float16)e1.x; a2[5] = (_Float16)e1.y;
            a2[6] = (_Float16)e1.z; a2[7] = (_Float16)e1.w;
        }

        // ---- layer 1: Z[16,128] = A1[16,96] @ Wm1 ----
        f32x4 z[8];
#pragma unroll
        for (int nt = 0; nt < 8; ++nt) z[nt] = (f32x4)0.f;
#pragma unroll
        for (int nt = 0; nt < 8; ++nt) {
            z[nt] = MFMA16(a0, *(const half8*)&wm1_sw[((0 * 8 + nt) * 64 + lane) * 8], z[nt]);
            z[nt] = MFMA16(a1, *(const half8*)&wm1_sw[((1 * 8 + nt) * 64 + lane) * 8], z[nt]);
            z[nt] = MFMA16(a2, *(const half8*)&wm1_sw[((2 * 8 + nt) * 64 + lane) * 8], z[nt]);
        }

        // ---- hf = relu(z+b) -> scratch -> A-frags; layer2 fwd ----
#pragma unroll
        for (int nt = 0; nt < 8; ++nt)
#pragma unroll
            for (int r = 0; r < 4; ++r)
                hs[(g * 4 + r) * SW + nt * 16 + c] = (_Float16)fmaxf(z[nt][r] + bm1v[nt], 0.f);
        half8 hA[4];
#pragma unroll
        for (int kt = 0; kt < 4; ++kt)
            hA[kt] = *(const half8*)&hs[c * SW + kt * 32 + g * 8];
        f32x4 m_f[4];
#pragma unroll
        for (int nt = 0; nt < 4; ++nt) m_f[nt] = (f32x4)0.f;
#pragma unroll
        for (int kt = 0; kt < 4; ++kt)
#pragma unroll
            for (int nt = 0; nt < 4; ++nt)
                m_f[nt] = MFMA16(hA[kt], *(const half8*)&wm2_sw[((kt * 4 + nt) * 64 + lane) * 8], m_f[nt]);

        // ---- hb = relu(b-z) -> scratch -> A-frags; layer2 bwd ----
#pragma unroll
        for (int nt = 0; nt < 8; ++nt)
#pragma unroll
            for (int r = 0; r < 4; ++r)
                hs[(g * 4 + r) * SW + nt * 16 + c] = (_Float16)fmaxf(bm1v[nt] - z[nt][r], 0.f);
#pragma unroll
        for (int kt = 0; kt < 4; ++kt)
            hA[kt] = *(const half8*)&hs[c * SW + kt * 32 + g * 8];
        f32x4 m_b[4];
#pragma unroll
        for (int nt = 0; nt < 4; ++nt) m_b[nt] = (f32x4)0.f;
#pragma unroll
        for (int kt = 0; kt < 4; ++kt)
#pragma unroll
            for (int nt = 0; nt < 4; ++nt)
                m_b[nt] = MFMA16(hA[kt], *(const half8*)&wm2_sw[((kt * 4 + nt) * 64 + lane) * 8], m_b[nt]);

        // ---- bias+relu, store msg, write m_sym scratch ----
#pragma unroll
        for (int nt = 0; nt < 4; ++nt)
#pragma unroll
            for (int r = 0; r < 4; ++r) {
                float mfv = fmaxf(m_f[nt][r] + bm2v[nt], 0.f);
                float mbv = fmaxf(m_b[nt][r] + bm2v[nt], 0.f);
                int row = g * 4 + r, col = nt * 16 + c;
                msg[(size_t)(eb + row) * 64 + col] = (_Float16)mfv;
                msg[(size_t)(NE + eb + row) * 64 + col] = (_Float16)mbv;
                hs[row * SW + col] = (_Float16)(mfv + mbv);
            }

        // ---- tension: D'[j, e] = Wt1^T @ m_sym^T ----
        half8 mB[2];
#pragma unroll
        for (int kt = 0; kt < 2; ++kt)
            mB[kt] = *(const half8*)&hs[c * SW + kt * 32 + g * 8];
        f32x4 ct[2];
        ct[0] = (f32x4)0.f; ct[1] = (f32x4)0.f;
#pragma unroll
        for (int jt = 0; jt < 2; ++jt)
#pragma unroll
            for (int kt = 0; kt < 2; ++kt)
                ct[jt] = MFMA16(*(const half8*)&wt1_sw[((jt * 2 + kt) * 64 + lane) * 8], mB[kt], ct[jt]);
        float p = 0.f;
#pragma unroll
        for (int jt = 0; jt < 2; ++jt)
#pragma unroll
            for (int r = 0; r < 4; ++r)
                p += fmaxf(ct[jt][r] + bt1v[jt * 4 + r], 0.f) * wt2v[jt * 4 + r];
        p += __shfl_xor(p, 16);
        p += __shfl_xor(p, 32);
        if (lane < 16) e_out[eb + c] = p + bt2v;
    }
}

// ===========================================================================
// Aggregation kernel: ONE WAVE PER NODE (50k waves -> TLP hides L3 latency).
// Half-wave per msg row; 4-deep unrolled gather (8 rows in flight).
// Writes aggr (f16, packed u32) into the x_out region of d_out (same bytes,
// consumed by node_mlp_kernel strictly before it overwrites with x_out).
// ===========================================================================
__global__ __launch_bounds__(256) void aggr_kernel(
    const _Float16* __restrict__ msg,
    const int* __restrict__ off, const int* __restrict__ slot,
    unsigned int* __restrict__ aggr_u32)
{
    const int lane = threadIdx.x & 63;
    const int wid  = threadIdx.x >> 6;
    const int n    = blockIdx.x * 4 + wid;
    if (n >= NN) return;

    const int b = off[n], en = off[n + 1];
    const unsigned int* msg_u32 = (const unsigned int*)msg;
    const int half = lane >> 5;
    const int col  = lane & 31;

    float a0 = 0.f, a1 = 0.f, a2 = 0.f, a3 = 0.f;
    float a4 = 0.f, a5 = 0.f, a6 = 0.f, a7 = 0.f;
    int it = b + half;
    for (; it + 6 < en; it += 8) {
        const int r0 = slot[it], r1 = slot[it + 2], r2 = slot[it + 4], r3 = slot[it + 6];
        const unsigned int d0 = msg_u32[(size_t)r0 * 32 + col];
        const unsigned int d1 = msg_u32[(size_t)r1 * 32 + col];
        const unsigned int d2 = msg_u32[(size_t)r2 * 32 + col];
        const unsigned int d3 = msg_u32[(size_t)r3 * 32 + col];
        a0 += h2f((unsigned short)(d0 & 0xffffu)); a1 += h2f((unsigned short)(d0 >> 16));
        a2 += h2f((unsigned short)(d1 & 0xffffu)); a3 += h2f((unsigned short)(d1 >> 16));
        a4 += h2f((unsigned short)(d2 & 0xffffu)); a5 += h2f((unsigned short)(d2 >> 16));
        a6 += h2f((unsigned short)(d3 & 0xffffu)); a7 += h2f((unsigned short)(d3 >> 16));
    }
    for (; it < en; it += 2) {
        const int r = slot[it];
        const unsigned int d = msg_u32[(size_t)r * 32 + col];
        a0 += h2f((unsigned short)(d & 0xffffu)); a1 += h2f((unsigned short)(d >> 16));
    }
    float lo = (a0 + a2) + (a4 + a6);
    float hi = (a1 + a3) + (a5 + a7);
    lo += __shfl_xor(lo, 32);
    hi += __shfl_xor(hi, 32);
    const float inv = 1.f / fmaxf((float)(en - b), 1.f);
    if (lane < 32) {
        unsigned short l16 = __builtin_bit_cast(unsigned short, (_Float16)(lo * inv));
        unsigned short h16 = __builtin_bit_cast(unsigned short, (_Float16)(hi * inv));
        aggr_u32[(size_t)n * 32 + lane] = (unsigned int)l16 | ((unsigned int)h16 << 16);
    }
}

// ===========================================================================
// Node MLP kernel: gather-free. [x | aggr][16,128] @ Wu1 -> relu -> @ Wu2.
// aggr aliases x_out byte-range; every aliased byte is read (into MFMA
// operands) before the dependent x_out store -> safe.
// ===========================================================================
#define SWN 72

__global__ __launch_bounds__(256) void node_mlp_kernel(
    const float* __restrict__ x,
    const float* __restrict__ Wu1, const float* __restrict__ bu1,
    const float* __restrict__ Wu2, const float* __restrict__ bu2,
    const _Float16* aggr, float* x_out)
{
    __shared__ __align__(16) _Float16 wu1_sw[4 * 4 * 64 * 8];   // 16 KB
    __shared__ __align__(16) _Float16 wu2_sw[2 * 2 * 64 * 8];   //  4 KB
    __shared__ __align__(16) _Float16 nscr[4 * 16 * SWN];       //  9 KB

    const int tid = threadIdx.x;
    for (int idx = tid; idx < 8192; idx += 256) {
        int i = idx & 7, l = (idx >> 3) & 63, nt = (idx >> 9) & 3, kt = idx >> 11;
        int k = kt * 32 + ((l >> 4) << 3) + i, n = nt * 16 + (l & 15);
        wu1_sw[idx] = (_Float16)Wu1[k * 64 + n];
    }
    for (int idx = tid; idx < 2048; idx += 256) {
        int i = idx & 7, l = (idx >> 3) & 63, kt = (idx >> 9) & 1, jt = idx >> 10;
        int k = kt * 32 + ((l >> 4) << 3) + i, j = jt * 16 + (l & 15);
        wu2_sw[idx] = (_Float16)Wu2[k * 32 + j];
    }
    __syncthreads();

    const int lane = tid & 63;
    const int g = lane >> 4;
    const int c = lane & 15;
    const int wid = tid >> 6;
    _Float16* ns = &nscr[wid * 16 * SWN];

    float bu1v[4], bu2v[8];
#pragma unroll
    for (int nt = 0; nt < 4; ++nt) bu1v[nt] = bu1[nt * 16 + c];
#pragma unroll
    for (int jt = 0; jt < 2; ++jt)
#pragma unroll
        for (int r = 0; r < 4; ++r) bu2v[jt * 4 + r] = bu2[jt * 16 + g * 4 + r];

    const float4* xp = (const float4*)x;

    const int gwave = blockIdx.x * 4 + wid;
    const int nwave = gridDim.x * 4;
    const int NB = NN / 16;   // 3125 exact

    for (int bt = gwave; bt < NB; bt += nwave) {
        const int nbase = bt * 16;
        const int nn_ = nbase + c;

        half8 af[4];
        {
            float4 x0 = xp[(size_t)nn_ * 16 + g * 2];
            float4 x1 = xp[(size_t)nn_ * 16 + g * 2 + 1];
            af[0][0] = (_Float16)x0.x; af[0][1] = (_Float16)x0.y;
            af[0][2] = (_Float16)x0.z; af[0][3] = (_Float16)x0.w;
            af[0][4] = (_Float16)x1.x; af[0][5] = (_Float16)x1.y;
            af[0][6] = (_Float16)x1.z; af[0][7] = (_Float16)x1.w;
            float4 x2 = xp[(size_t)nn_ * 16 + 8 + g * 2];
            float4 x3 = xp[(size_t)nn_ * 16 + 8 + g * 2 + 1];
            af[1][0] = (_Float16)x2.x; af[1][1] = (_Float16)x2.y;
            af[1][2] = (_Float16)x2.z; af[1][3] = (_Float16)x2.w;
            af[1][4] = (_Float16)x3.x; af[1][5] = (_Float16)x3.y;
            af[1][6] = (_Float16)x3.z; af[1][7] = (_Float16)x3.w;
        }
        af[2] = *(const half8*)&aggr[(size_t)nn_ * 64 + g * 8];
        af[3] = *(const half8*)&aggr[(size_t)nn_ * 64 + 32 + g * 8];

        f32x4 hu[4];
#pragma unroll
        for (int nt = 0; nt < 4; ++nt) hu[nt] = (f32x4)0.f;
#pragma unroll
        for (int kt = 0; kt < 4; ++kt)
#pragma unroll
            for (int nt = 0; nt < 4; ++nt)
                hu[nt] = MFMA16(af[kt], *(const half8*)&wu1_sw[((kt * 4 + nt) * 64 + lane) * 8], hu[nt]);

#pragma unroll
        for (int nt = 0; nt < 4; ++nt)
#pragma unroll
            for (int r = 0; r < 4; ++r)
                ns[(g * 4 + r) * SWN + nt * 16 + c] = (_Float16)fmaxf(hu[nt][r] + bu1v[nt], 0.f);

        half8 hB[2];
#pragma unroll
        for (int kt = 0; kt < 2; ++kt)
            hB[kt] = *(const half8*)&ns[c * SWN + kt * 32 + g * 8];
        f32x4 co[2];
        co[0] = (f32x4)0.f; co[1] = (f32x4)0.f;
#pragma unroll
        for (int jt = 0; jt < 2; ++jt)
#pragma unroll
            for (int kt = 0; kt < 2; ++kt)
                co[jt] = MFMA16(*(const half8*)&wu2_sw[((jt * 2 + kt) * 64 + lane) * 8], hB[kt], co[jt]);

#pragma unroll
        for (int jt = 0; jt < 2; ++jt)
#pragma unroll
            for (int r = 0; r < 4; ++r)
                x_out[(size_t)nn_ * 32 + jt * 16 + g * 4 + r] = co[jt][r] + bu2v[jt * 4 + r];
    }
}

extern "C" void kernel_launch(void* const* d_in, const int* in_sizes, int n_in,
                              void* d_out, int out_size, void* d_ws, size_t ws_size,
                              hipStream_t stream) {
    const float* x   = (const float*)d_in[0];
    const int*   ei  = (const int*)d_in[1];
    const float* ea  = (const float*)d_in[2];
    const float* Wm1 = (const float*)d_in[3];
    const float* bm1 = (const float*)d_in[4];
    const float* Wm2 = (const float*)d_in[5];
    const float* bm2 = (const float*)d_in[6];
    const float* Wu1 = (const float*)d_in[7];
    const float* bu1 = (const float*)d_in[8];
    const float* Wu2 = (const float*)d_in[9];
    const float* bu2 = (const float*)d_in[10];
    const float* Wt1 = (const float*)d_in[11];
    const float* bt1 = (const float*)d_in[12];
    const float* Wt2 = (const float*)d_in[13];
    const float* bt2 = (const float*)d_in[14];

    float* x_out = (float*)d_out;
    float* e_out = x_out + (size_t)NN * 32;

    const size_t msg_bytes = (size_t)2 * NE * 64 * sizeof(_Float16); // 128 MB
    _Float16* msg = (_Float16*)d_ws;
    int* slot   = (int*)((char*)d_ws + msg_bytes);
    int* deg    = slot + (size_t)2 * NE;
    int* off    = deg + NN;
    int* cursor = off + NN + 1;

    hipMemsetAsync(deg, 0, (size_t)NN * sizeof(int), stream);
    hist_kernel<<<(NE + 1023) / 1024, 1024, 0, stream>>>(ei, deg);
    scan_kernel<<<1, 1024, 0, stream>>>(deg, off, cursor);
    place_kernel<<<(NE + 1023) / 1024, 1024, 0, stream>>>(ei, cursor, slot);

    edge_mfma_kernel<<<1024, 512, 0, stream>>>(x, ei, ea, Wm1, bm1, Wm2, bm2,
                                               Wt1, bt1, Wt2, bt2, msg, e_out);

    // aggr (f16) aliases the x_out region of d_out (same byte extent)
    aggr_kernel<<<(NN + 3) / 4, 256, 0, stream>>>(msg, off, slot,
                                                  (unsigned int*)d_out);
    node_mlp_kernel<<<391, 256, 0, stream>>>(x, Wu1, bu1, Wu2, bu2,
                                             (const _Float16*)d_out, x_out);
}

// Round 5
// 311.496 us; speedup vs baseline: 31.6407x; 1.4124x over previous
//
#include <hip/hip_runtime.h>
#include <hip/hip_bf16.h>

// Problem constants (match reference)
#define NN 50000
#define NE 500000
// D_NODE=64, D_EDGE=8, D_MSG=64, H_MSG=128, H_UPD=64, H_TEN=32, D_OUT=32

typedef _Float16 half8 __attribute__((ext_vector_type(8)));
typedef float f32x4 __attribute__((ext_vector_type(4)));

#define MFMA16(a, b, c) __builtin_amdgcn_mfma_f32_16x16x32_f16(a, b, c, 0, 0, 0)

__device__ __forceinline__ float h2f(unsigned short b) {
    return (float)__builtin_bit_cast(_Float16, b);
}

// ===========================================================================
// CSR-build: hist -> 3-phase hierarchical scan -> place (inverse perm pos[])
// Directed edge d in [0,2E): d<NE is fwd (tgt=ei[NE+d]); d>=NE bwd (tgt=ei[d-NE])
// ===========================================================================
__global__ void hist_kernel(const int* __restrict__ ei, int* __restrict__ deg) {
    int e = blockIdx.x * blockDim.x + threadIdx.x;
    if (e < NE) {
        atomicAdd(&deg[ei[NE + e]], 1);   // fwd message targets t
        atomicAdd(&deg[ei[e]], 1);        // bwd message targets s
    }
}

#define SCAN_NBLK ((NN + 255) / 256)   // 196

__global__ __launch_bounds__(256) void scan1_kernel(
    const int* __restrict__ deg, int* __restrict__ off, int* __restrict__ part) {
    __shared__ int sh[256];
    const int t = threadIdx.x;
    const int i = blockIdx.x * 256 + t;
    const int v = (i < NN) ? deg[i] : 0;
    sh[t] = v;
    __syncthreads();
    for (int d = 1; d < 256; d <<= 1) {
        int u = (t >= d) ? sh[t - d] : 0;
        __syncthreads();
        sh[t] += u;
        __syncthreads();
    }
    if (i < NN) off[i] = sh[t] - v;            // exclusive local
    if (t == 255) part[blockIdx.x] = sh[255];  // block total
}

__global__ __launch_bounds__(256) void scan2_kernel(int* __restrict__ part) {
    __shared__ int sh[256];
    const int t = threadIdx.x;
    const int v = (t < SCAN_NBLK) ? part[t] : 0;
    sh[t] = v;
    __syncthreads();
    for (int d = 1; d < 256; d <<= 1) {
        int u = (t >= d) ? sh[t - d] : 0;
        __syncthreads();
        sh[t] += u;
        __syncthreads();
    }
    if (t < SCAN_NBLK) part[t] = sh[t] - v;    // exclusive
}

__global__ __launch_bounds__(256) void scan3_kernel(
    int* __restrict__ off, int* __restrict__ cursor, const int* __restrict__ part) {
    const int t = threadIdx.x;
    const int i = blockIdx.x * 256 + t;
    if (i < NN) {
        const int o = off[i] + part[blockIdx.x];
        off[i] = o;
        cursor[i] = o;
    }
    if (i == 0) off[NN] = 2 * NE;
}

__global__ void place_kernel(const int* __restrict__ ei,
                             int* __restrict__ cursor, int* __restrict__ pos) {
    int e = blockIdx.x * blockDim.x + threadIdx.x;
    if (e < NE) {
        int t = ei[NE + e]; pos[e]      = atomicAdd(&cursor[t], 1);  // fwd slot
        int s = ei[e];      pos[NE + e] = atomicAdd(&cursor[s], 1);  // bwd slot
    }
}

// ===========================================================================
// Edge kernel (MFMA): 8 waves/block (512 thr), batches of 16 edge-pairs.
// Layouts (HW-verified round 3):
//   A-frag: lane l holds A[row=l&15][k=(l>>4)*8+i]
//   B-frag: lane l holds B[k=(l>>4)*8+i][col=l&15]
//   C/D   : lane l holds D[row=(l>>4)*4+r][col=l&15]
// Messages are written TARGET-SORTED (msg[pos[d]]) so aggr streams them.
// ===========================================================================
#define SW 136   // scratch row stride in halfs (272 B, 16B-aligned rows)
#define EW 8     // waves per block

__global__ __launch_bounds__(512) void edge_mfma_kernel(
    const float* __restrict__ x, const int* __restrict__ ei,
    const float* __restrict__ ea, const int* __restrict__ pos,
    const float* __restrict__ Wm1, const float* __restrict__ bm1,
    const float* __restrict__ Wm2, const float* __restrict__ bm2,
    const float* __restrict__ Wt1, const float* __restrict__ bt1,
    const float* __restrict__ Wt2, const float* __restrict__ bt2,
    _Float16* __restrict__ msg, float* __restrict__ e_out)
{
    __shared__ __align__(16) _Float16 wm1_sw[3 * 8 * 64 * 8];   // 24 KB
    __shared__ __align__(16) _Float16 wm2_sw[4 * 4 * 64 * 8];   // 16 KB
    __shared__ __align__(16) _Float16 wt1_sw[2 * 2 * 64 * 8];   //  4 KB
    __shared__ __align__(16) _Float16 hscr[EW * 16 * SW];       // 34 KB

    const int tid = threadIdx.x;
    for (int idx = tid; idx < 12288; idx += 512) {   // Wm1 [72,128] pad K->96
        int i = idx & 7, l = (idx >> 3) & 63, nt = (idx >> 9) & 7, kt = idx >> 12;
        int k = kt * 32 + ((l >> 4) << 3) + i, n = nt * 16 + (l & 15);
        wm1_sw[idx] = (k < 72) ? (_Float16)Wm1[k * 128 + n] : (_Float16)0.f;
    }
    for (int idx = tid; idx < 8192; idx += 512) {    // Wm2 [128,64]
        int i = idx & 7, l = (idx >> 3) & 63, nt = (idx >> 9) & 3, kt = idx >> 11;
        int k = kt * 32 + ((l >> 4) << 3) + i, n = nt * 16 + (l & 15);
        wm2_sw[idx] = (_Float16)Wm2[k * 64 + n];
    }
    for (int idx = tid; idx < 2048; idx += 512) {    // Wt1^T as A-frags [32,64]
        int i = idx & 7, l = (idx >> 3) & 63, kt = (idx >> 9) & 1, jt = idx >> 10;
        int k = kt * 32 + ((l >> 4) << 3) + i, j = jt * 16 + (l & 15);
        wt1_sw[idx] = (_Float16)Wt1[k * 32 + j];
    }
    __syncthreads();

    const int lane = tid & 63;
    const int g = lane >> 4;
    const int c = lane & 15;
    const int wid = tid >> 6;
    _Float16* hs = &hscr[wid * 16 * SW];

    float bm1v[8], bm2v[4], bt1v[8], wt2v[8];
#pragma unroll
    for (int nt = 0; nt < 8; ++nt) bm1v[nt] = bm1[nt * 16 + c];
#pragma unroll
    for (int nt = 0; nt < 4; ++nt) bm2v[nt] = bm2[nt * 16 + c];
#pragma unroll
    for (int jt = 0; jt < 2; ++jt)
#pragma unroll
        for (int r = 0; r < 4; ++r) {
            int j = jt * 16 + g * 4 + r;
            bt1v[jt * 4 + r] = bt1[j];
            wt2v[jt * 4 + r] = Wt2[j];
        }
    const float bt2v = bt2[0];

    const float4* xp = (const float4*)x;
    const float4* eap = (const float4*)ea;

    const int gwave = blockIdx.x * EW + wid;
    const int nwave = gridDim.x * EW;
    const int NB = NE / 16;   // 31250 exact

    for (int bt = gwave; bt < NB; bt += nwave) {
        const int eb = bt * 16;
        const int e = eb + c;
        const int sv = ei[e];
        const int tv = ei[NE + e];

        // sorted positions for this lane's 4 output rows (fwd & bwd)
        int pf[4], pb[4];
#pragma unroll
        for (int r = 0; r < 4; ++r) {
            pf[r] = pos[eb + g * 4 + r];
            pb[r] = pos[NE + eb + g * 4 + r];
        }

        // ---- build A1 fragments (diff in k<64, ea in k=64..71, pad 0) ----
        half8 a0, a1, a2;
        {
            float4 t0 = xp[(size_t)tv * 16 + g * 2];
            float4 t1 = xp[(size_t)tv * 16 + g * 2 + 1];
            float4 s0 = xp[(size_t)sv * 16 + g * 2];
            float4 s1 = xp[(size_t)sv * 16 + g * 2 + 1];
            a0[0] = (_Float16)(t0.x - s0.x); a0[1] = (_Float16)(t0.y - s0.y);
            a0[2] = (_Float16)(t0.z - s0.z); a0[3] = (_Float16)(t0.w - s0.w);
            a0[4] = (_Float16)(t1.x - s1.x); a0[5] = (_Float16)(t1.y - s1.y);
            a0[6] = (_Float16)(t1.z - s1.z); a0[7] = (_Float16)(t1.w - s1.w);
            float4 t2 = xp[(size_t)tv * 16 + 8 + g * 2];
            float4 t3 = xp[(size_t)tv * 16 + 8 + g * 2 + 1];
            float4 s2 = xp[(size_t)sv * 16 + 8 + g * 2];
            float4 s3 = xp[(size_t)sv * 16 + 8 + g * 2 + 1];
            a1[0] = (_Float16)(t2.x - s2.x); a1[1] = (_Float16)(t2.y - s2.y);
            a1[2] = (_Float16)(t2.z - s2.z); a1[3] = (_Float16)(t2.w - s2.w);
            a1[4] = (_Float16)(t3.x - s3.x); a1[5] = (_Float16)(t3.y - s3.y);
            a1[6] = (_Float16)(t3.z - s3.z); a1[7] = (_Float16)(t3.w - s3.w);
        }
        a2 = (half8)(_Float16)0.f;
        if (g == 0) {
            float4 e0 = eap[(size_t)e * 2];
            float4 e1 = eap[(size_t)e * 2 + 1];
            a2[0] = (_Float16)e0.x; a2[1] = (_Float16)e0.y;
            a2[2] = (_Float16)e0.z; a2[3] = (_Float16)e0.w;
            a2[4] = (_Float16)e1.x; a2[5] = (_Float16)e1.y;
            a2[6] = (_Float16)e1.z; a2[7] = (_Float16)e1.w;
        }

        // ---- layer 1: Z[16,128] = A1[16,96] @ Wm1 ----
        f32x4 z[8];
#pragma unroll
        for (int nt = 0; nt < 8; ++nt) z[nt] = (f32x4)0.f;
#pragma unroll
        for (int nt = 0; nt < 8; ++nt) {
            z[nt] = MFMA16(a0, *(const half8*)&wm1_sw[((0 * 8 + nt) * 64 + lane) * 8], z[nt]);
            z[nt] = MFMA16(a1, *(const half8*)&wm1_sw[((1 * 8 + nt) * 64 + lane) * 8], z[nt]);
            z[nt] = MFMA16(a2, *(const half8*)&wm1_sw[((2 * 8 + nt) * 64 + lane) * 8], z[nt]);
        }

        // ---- hf = relu(z+b) -> scratch -> A-frags; layer2 fwd ----
#pragma unroll
        for (int nt = 0; nt < 8; ++nt)
#pragma unroll
            for (int r = 0; r < 4; ++r)
                hs[(g * 4 + r) * SW + nt * 16 + c] = (_Float16)fmaxf(z[nt][r] + bm1v[nt], 0.f);
        half8 hA[4];
#pragma unroll
        for (int kt = 0; kt < 4; ++kt)
            hA[kt] = *(const half8*)&hs[c * SW + kt * 32 + g * 8];
        f32x4 m_f[4];
#pragma unroll
        for (int nt = 0; nt < 4; ++nt) m_f[nt] = (f32x4)0.f;
#pragma unroll
        for (int kt = 0; kt < 4; ++kt)
#pragma unroll
            for (int nt = 0; nt < 4; ++nt)
                m_f[nt] = MFMA16(hA[kt], *(const half8*)&wm2_sw[((kt * 4 + nt) * 64 + lane) * 8], m_f[nt]);

        // ---- hb = relu(b-z) -> scratch -> A-frags; layer2 bwd ----
#pragma unroll
        for (int nt = 0; nt < 8; ++nt)
#pragma unroll
            for (int r = 0; r < 4; ++r)
                hs[(g * 4 + r) * SW + nt * 16 + c] = (_Float16)fmaxf(bm1v[nt] - z[nt][r], 0.f);
#pragma unroll
        for (int kt = 0; kt < 4; ++kt)
            hA[kt] = *(const half8*)&hs[c * SW + kt * 32 + g * 8];
        f32x4 m_b[4];
#pragma unroll
        for (int nt = 0; nt < 4; ++nt) m_b[nt] = (f32x4)0.f;
#pragma unroll
        for (int kt = 0; kt < 4; ++kt)
#pragma unroll
            for (int nt = 0; nt < 4; ++nt)
                m_b[nt] = MFMA16(hA[kt], *(const half8*)&wm2_sw[((kt * 4 + nt) * 64 + lane) * 8], m_b[nt]);

        // ---- bias+relu, store msg at SORTED positions, m_sym -> scratch ----
#pragma unroll
        for (int nt = 0; nt < 4; ++nt)
#pragma unroll
            for (int r = 0; r < 4; ++r) {
                float mfv = fmaxf(m_f[nt][r] + bm2v[nt], 0.f);
                float mbv = fmaxf(m_b[nt][r] + bm2v[nt], 0.f);
                int row = g * 4 + r, col = nt * 16 + c;
                msg[(size_t)pf[r] * 64 + col] = (_Float16)mfv;
                msg[(size_t)pb[r] * 64 + col] = (_Float16)mbv;
                hs[row * SW + col] = (_Float16)(mfv + mbv);
            }

        // ---- tension: D'[j, e] = Wt1^T @ m_sym^T ----
        half8 mB[2];
#pragma unroll
        for (int kt = 0; kt < 2; ++kt)
            mB[kt] = *(const half8*)&hs[c * SW + kt * 32 + g * 8];
        f32x4 ct[2];
        ct[0] = (f32x4)0.f; ct[1] = (f32x4)0.f;
#pragma unroll
        for (int jt = 0; jt < 2; ++jt)
#pragma unroll
            for (int kt = 0; kt < 2; ++kt)
                ct[jt] = MFMA16(*(const half8*)&wt1_sw[((jt * 2 + kt) * 64 + lane) * 8], mB[kt], ct[jt]);
        float p = 0.f;
#pragma unroll
        for (int jt = 0; jt < 2; ++jt)
#pragma unroll
            for (int r = 0; r < 4; ++r)
                p += fmaxf(ct[jt][r] + bt1v[jt * 4 + r], 0.f) * wt2v[jt * 4 + r];
        p += __shfl_xor(p, 16);
        p += __shfl_xor(p, 32);
        if (lane < 16) e_out[eb + c] = p + bt2v;
    }
}

// ===========================================================================
// Aggregation kernel: ONE WAVE PER NODE. msg is target-sorted, so each node
// reads a CONTIGUOUS block of rows [off[n], off[n+1]) -- pure streaming.
// Writes aggr (f16, packed u32) into the x_out region of d_out.
// ===========================================================================
__global__ __launch_bounds__(256) void aggr_kernel(
    const _Float16* __restrict__ msg, const int* __restrict__ off,
    unsigned int* __restrict__ aggr_u32)
{
    const int lane = threadIdx.x & 63;
    const int wid  = threadIdx.x >> 6;
    const int n    = blockIdx.x * 4 + wid;
    if (n >= NN) return;

    const int b = off[n], en = off[n + 1];
    const unsigned int* msg_u32 = (const unsigned int*)msg;
    const int half = lane >> 5;
    const int col  = lane & 31;

    float a0 = 0.f, a1 = 0.f, a2 = 0.f, a3 = 0.f;
    float a4 = 0.f, a5 = 0.f, a6 = 0.f, a7 = 0.f;
    int it = b + half;
    for (; it + 6 < en; it += 8) {
        const unsigned int d0 = msg_u32[(size_t)it * 32 + col];
        const unsigned int d1 = msg_u32[(size_t)(it + 2) * 32 + col];
        const unsigned int d2 = msg_u32[(size_t)(it + 4) * 32 + col];
        const unsigned int d3 = msg_u32[(size_t)(it + 6) * 32 + col];
        a0 += h2f((unsigned short)(d0 & 0xffffu)); a1 += h2f((unsigned short)(d0 >> 16));
        a2 += h2f((unsigned short)(d1 & 0xffffu)); a3 += h2f((unsigned short)(d1 >> 16));
        a4 += h2f((unsigned short)(d2 & 0xffffu)); a5 += h2f((unsigned short)(d2 >> 16));
        a6 += h2f((unsigned short)(d3 & 0xffffu)); a7 += h2f((unsigned short)(d3 >> 16));
    }
    for (; it < en; it += 2) {
        const unsigned int d = msg_u32[(size_t)it * 32 + col];
        a0 += h2f((unsigned short)(d & 0xffffu)); a1 += h2f((unsigned short)(d >> 16));
    }
    float lo = (a0 + a2) + (a4 + a6);
    float hi = (a1 + a3) + (a5 + a7);
    lo += __shfl_xor(lo, 32);
    hi += __shfl_xor(hi, 32);
    const float inv = 1.f / fmaxf((float)(en - b), 1.f);
    if (lane < 32) {
        unsigned short l16 = __builtin_bit_cast(unsigned short, (_Float16)(lo * inv));
        unsigned short h16 = __builtin_bit_cast(unsigned short, (_Float16)(hi * inv));
        aggr_u32[(size_t)n * 32 + lane] = (unsigned int)l16 | ((unsigned int)h16 << 16);
    }
}

// ===========================================================================
// Node MLP kernel: gather-free. [x | aggr][16,128] @ Wu1 -> relu -> @ Wu2.
// aggr aliases x_out bytes; each node's aggr bytes are read (into MFMA
// operands) by the same wave before the dependent x_out store -> safe.
// ===========================================================================
#define SWN 72

__global__ __launch_bounds__(256) void node_mlp_kernel(
    const float* __restrict__ x,
    const float* __restrict__ Wu1, const float* __restrict__ bu1,
    const float* __restrict__ Wu2, const float* __restrict__ bu2,
    const _Float16* aggr, float* x_out)
{
    __shared__ __align__(16) _Float16 wu1_sw[4 * 4 * 64 * 8];   // 16 KB
    __shared__ __align__(16) _Float16 wu2_sw[2 * 2 * 64 * 8];   //  4 KB
    __shared__ __align__(16) _Float16 nscr[4 * 16 * SWN];       //  9 KB

    const int tid = threadIdx.x;
    for (int idx = tid; idx < 8192; idx += 256) {
        int i = idx & 7, l = (idx >> 3) & 63, nt = (idx >> 9) & 3, kt = idx >> 11;
        int k = kt * 32 + ((l >> 4) << 3) + i, n = nt * 16 + (l & 15);
        wu1_sw[idx] = (_Float16)Wu1[k * 64 + n];
    }
    for (int idx = tid; idx < 2048; idx += 256) {
        int i = idx & 7, l = (idx >> 3) & 63, kt = (idx >> 9) & 1, jt = idx >> 10;
        int k = kt * 32 + ((l >> 4) << 3) + i, j = jt * 16 + (l & 15);
        wu2_sw[idx] = (_Float16)Wu2[k * 32 + j];
    }
    __syncthreads();

    const int lane = tid & 63;
    const int g = lane >> 4;
    const int c = lane & 15;
    const int wid = tid >> 6;
    _Float16* ns = &nscr[wid * 16 * SWN];

    float bu1v[4], bu2v[8];
#pragma unroll
    for (int nt = 0; nt < 4; ++nt) bu1v[nt] = bu1[nt * 16 + c];
#pragma unroll
    for (int jt = 0; jt < 2; ++jt)
#pragma unroll
        for (int r = 0; r < 4; ++r) bu2v[jt * 4 + r] = bu2[jt * 16 + g * 4 + r];

    const float4* xp = (const float4*)x;

    const int gwave = blockIdx.x * 4 + wid;
    const int nwave = gridDim.x * 4;
    const int NB = NN / 16;   // 3125 exact

    for (int bt = gwave; bt < NB; bt += nwave) {
        const int nbase = bt * 16;
        const int nn_ = nbase + c;

        half8 af[4];
        {
            float4 x0 = xp[(size_t)nn_ * 16 + g * 2];
            float4 x1 = xp[(size_t)nn_ * 16 + g * 2 + 1];
            af[0][0] = (_Float16)x0.x; af[0][1] = (_Float16)x0.y;
            af[0][2] = (_Float16)x0.z; af[0][3] = (_Float16)x0.w;
            af[0][4] = (_Float16)x1.x; af[0][5] = (_Float16)x1.y;
            af[0][6] = (_Float16)x1.z; af[0][7] = (_Float16)x1.w;
            float4 x2 = xp[(size_t)nn_ * 16 + 8 + g * 2];
            float4 x3 = xp[(size_t)nn_ * 16 + 8 + g * 2 + 1];
            af[1][0] = (_Float16)x2.x; af[1][1] = (_Float16)x2.y;
            af[1][2] = (_Float16)x2.z; af[1][3] = (_Float16)x2.w;
            af[1][4] = (_Float16)x3.x; af[1][5] = (_Float16)x3.y;
            af[1][6] = (_Float16)x3.z; af[1][7] = (_Float16)x3.w;
        }
        af[2] = *(const half8*)&aggr[(size_t)nn_ * 64 + g * 8];
        af[3] = *(const half8*)&aggr[(size_t)nn_ * 64 + 32 + g * 8];

        f32x4 hu[4];
#pragma unroll
        for (int nt = 0; nt < 4; ++nt) hu[nt] = (f32x4)0.f;
#pragma unroll
        for (int kt = 0; kt < 4; ++kt)
#pragma unroll
            for (int nt = 0; nt < 4; ++nt)
                hu[nt] = MFMA16(af[kt], *(const half8*)&wu1_sw[((kt * 4 + nt) * 64 + lane) * 8], hu[nt]);

#pragma unroll
        for (int nt = 0; nt < 4; ++nt)
#pragma unroll
            for (int r = 0; r < 4; ++r)
                ns[(g * 4 + r) * SWN + nt * 16 + c] = (_Float16)fmaxf(hu[nt][r] + bu1v[nt], 0.f);

        half8 hB[2];
#pragma unroll
        for (int kt = 0; kt < 2; ++kt)
            hB[kt] = *(const half8*)&ns[c * SWN + kt * 32 + g * 8];
        f32x4 co[2];
        co[0] = (f32x4)0.f; co[1] = (f32x4)0.f;
#pragma unroll
        for (int jt = 0; jt < 2; ++jt)
#pragma unroll
            for (int kt = 0; kt < 2; ++kt)
                co[jt] = MFMA16(*(const half8*)&wu2_sw[((jt * 2 + kt) * 64 + lane) * 8], hB[kt], co[jt]);

#pragma unroll
        for (int jt = 0; jt < 2; ++jt)
#pragma unroll
            for (int r = 0; r < 4; ++r)
                x_out[(size_t)nn_ * 32 + jt * 16 + g * 4 + r] = co[jt][r] + bu2v[jt * 4 + r];
    }
}

extern "C" void kernel_launch(void* const* d_in, const int* in_sizes, int n_in,
                              void* d_out, int out_size, void* d_ws, size_t ws_size,
                              hipStream_t stream) {
    const float* x   = (const float*)d_in[0];
    const int*   ei  = (const int*)d_in[1];
    const float* ea  = (const float*)d_in[2];
    const float* Wm1 = (const float*)d_in[3];
    const float* bm1 = (const float*)d_in[4];
    const float* Wm2 = (const float*)d_in[5];
    const float* bm2 = (const float*)d_in[6];
    const float* Wu1 = (const float*)d_in[7];
    const float* bu1 = (const float*)d_in[8];
    const float* Wu2 = (const float*)d_in[9];
    const float* bu2 = (const float*)d_in[10];
    const float* Wt1 = (const float*)d_in[11];
    const float* bt1 = (const float*)d_in[12];
    const float* Wt2 = (const float*)d_in[13];
    const float* bt2 = (const float*)d_in[14];

    float* x_out = (float*)d_out;
    float* e_out = x_out + (size_t)NN * 32;

    const size_t msg_bytes = (size_t)2 * NE * 64 * sizeof(_Float16); // 128 MB
    _Float16* msg = (_Float16*)d_ws;
    int* pos    = (int*)((char*)d_ws + msg_bytes);  // [2E] inverse permutation
    int* deg    = pos + (size_t)2 * NE;             // [NN]
    int* off    = deg + NN;                         // [NN+1]
    int* cursor = off + NN + 1;                     // [NN]
    int* part   = cursor + NN;                      // [SCAN_NBLK]

    hipMemsetAsync(deg, 0, (size_t)NN * sizeof(int), stream);
    hist_kernel<<<(NE + 1023) / 1024, 1024, 0, stream>>>(ei, deg);
    scan1_kernel<<<SCAN_NBLK, 256, 0, stream>>>(deg, off, part);
    scan2_kernel<<<1, 256, 0, stream>>>(part);
    scan3_kernel<<<SCAN_NBLK, 256, 0, stream>>>(off, cursor, part);
    place_kernel<<<(NE + 1023) / 1024, 1024, 0, stream>>>(ei, cursor, pos);

    edge_mfma_kernel<<<1024, 512, 0, stream>>>(x, ei, ea, pos, Wm1, bm1, Wm2, bm2,
                                               Wt1, bt1, Wt2, bt2, msg, e_out);

    // aggr (f16) aliases the x_out region of d_out (same byte extent)
    aggr_kernel<<<(NN + 3) / 4, 256, 0, stream>>>(msg, off, (unsigned int*)d_out);
    node_mlp_kernel<<<391, 256, 0, stream>>>(x, Wu1, bu1, Wu2, bu2,
                                             (const _Float16*)d_out, x_out);
}